// Round 1
// baseline (742.033 us; speedup 1.0000x reference)
//
#include <hip/hip_runtime.h>
#include <cstdint>
#include <cstddef>

#define N_NODES 50000
#define N_EDGES 800000
#define DIM_IN 128
#define H_DIM 64
#define N_GRAPHS 256
#define EPS_BN 1e-5f

// ---------- preprocessing ----------

__global__ void count_edges_k(const int* __restrict__ dst, int* __restrict__ counts) {
    int e = blockIdx.x * blockDim.x + threadIdx.x;
    if (e < N_EDGES) atomicAdd(&counts[dst[e]], 1);
}

__global__ void scan_block_k(const int* __restrict__ counts, int* __restrict__ offsets,
                             int* __restrict__ blocksums) {
    __shared__ int sh[1024];
    int i = blockIdx.x * 1024 + threadIdx.x;
    int v = (i < N_NODES) ? counts[i] : 0;
    sh[threadIdx.x] = v;
    __syncthreads();
    for (int off = 1; off < 1024; off <<= 1) {
        int t = (threadIdx.x >= off) ? sh[threadIdx.x - off] : 0;
        __syncthreads();
        sh[threadIdx.x] += t;
        __syncthreads();
    }
    if (i < N_NODES) offsets[i] = sh[threadIdx.x] - v;   // exclusive
    if (threadIdx.x == 1023) blocksums[blockIdx.x] = sh[1023];
}

__global__ void scan_sums_k(int* blocksums, int nb) {
    if (threadIdx.x == 0 && blockIdx.x == 0) {
        int run = 0;
        for (int b = 0; b < nb; b++) { int t = blocksums[b]; blocksums[b] = run; run += t; }
    }
}

__global__ void finalize_offsets_k(int* __restrict__ offsets, int* __restrict__ cursor,
                                   const int* __restrict__ counts,
                                   const int* __restrict__ blocksums,
                                   float* __restrict__ dinv) {
    int i = blockIdx.x * blockDim.x + threadIdx.x;
    if (i >= N_NODES) return;
    int o = offsets[i] + blocksums[i >> 10];
    offsets[i] = o;
    cursor[i] = o;
    dinv[i] = rsqrtf((float)(counts[i] + 1));   // +1 self loop, always >= 1
}

__global__ void fill_csr_k(const int* __restrict__ src, const int* __restrict__ dst,
                           int* __restrict__ cursor, int* __restrict__ ssrc) {
    int e = blockIdx.x * blockDim.x + threadIdx.x;
    if (e >= N_EDGES) return;
    int d = dst[e];
    int pos = atomicAdd(&cursor[d], 1);
    ssrc[pos] = src[e];
}

__global__ void graph_cnt_k(const int* __restrict__ batch, float* __restrict__ cnt) {
    int n = blockIdx.x * blockDim.x + threadIdx.x;
    if (n < N_NODES) atomicAdd(&cnt[batch[n]], 1.0f);
}

// ---------- per-layer ----------

// one wave per node; lane = output channel (H_DIM == 64 == wave size)
template<int K>
__global__ void gemm_k(const float* __restrict__ Z, int ldz,
                       const float* __restrict__ W, float* __restrict__ h) {
    int wid = (blockIdx.x * blockDim.x + threadIdx.x) >> 6;
    int lane = threadIdx.x & 63;
    if (wid >= N_NODES) return;
    const float* zr = Z + (size_t)wid * ldz;
    float acc = 0.f;
    #pragma unroll
    for (int k = 0; k < K; k++) acc = fmaf(zr[k], W[k * H_DIM + lane], acc);
    h[(size_t)wid * H_DIM + lane] = acc;
}

// one wave per dst node; lane = feature; CSR gather of h[src] rows
__global__ void aggregate_k(const float* __restrict__ h, const float* __restrict__ dinv,
                            const int* __restrict__ offsets, const int* __restrict__ counts,
                            const int* __restrict__ ssrc, const float* __restrict__ bias,
                            float* __restrict__ zb) {
    int wid = (blockIdx.x * blockDim.x + threadIdx.x) >> 6;
    int lane = threadIdx.x & 63;
    if (wid >= N_NODES) return;
    float di = dinv[wid];
    float acc = h[(size_t)wid * H_DIM + lane] * di * di;   // self loop
    int s0 = offsets[wid];
    int ce = counts[wid];
    for (int e = 0; e < ce; e++) {
        int s = ssrc[s0 + e];
        acc += h[(size_t)s * H_DIM + lane] * (dinv[s] * di);
    }
    acc += bias[lane];
    zb[(size_t)wid * H_DIM + lane] = fmaxf(acc, 0.f);
}

__global__ void bn_stats_k(const float* __restrict__ zb, float* __restrict__ sums,
                           float* __restrict__ sumsq) {
    int c = threadIdx.x & 63;
    int rowStart = blockIdx.x * 4 + (threadIdx.x >> 6);
    float s = 0.f, q = 0.f;
    for (int r = rowStart; r < N_NODES; r += gridDim.x * 4) {
        float v = zb[(size_t)r * H_DIM + c];
        s += v; q += v * v;
    }
    __shared__ float sh_s[256], sh_q[256];
    sh_s[threadIdx.x] = s; sh_q[threadIdx.x] = q;
    __syncthreads();
    if (threadIdx.x < 64) {
        s = sh_s[threadIdx.x] + sh_s[threadIdx.x + 64] + sh_s[threadIdx.x + 128] + sh_s[threadIdx.x + 192];
        q = sh_q[threadIdx.x] + sh_q[threadIdx.x + 64] + sh_q[threadIdx.x + 128] + sh_q[threadIdx.x + 192];
        atomicAdd(&sums[c], s);
        atomicAdd(&sumsq[c], q);
    }
}

__global__ void bn_finalize_k(const float* __restrict__ sums, const float* __restrict__ sumsq,
                              const float* __restrict__ gamma, const float* __restrict__ beta,
                              float* __restrict__ scale, float* __restrict__ shift) {
    int c = threadIdx.x;
    if (c >= H_DIM) return;
    float mu = sums[c] * (1.0f / N_NODES);
    float var = sumsq[c] * (1.0f / N_NODES) - mu * mu;
    float sc = gamma[c] * rsqrtf(var + EPS_BN);
    scale[c] = sc;
    shift[c] = beta[c] - mu * sc;
}

__global__ void bn_apply_k(const float* __restrict__ zb, const float* __restrict__ scale,
                           const float* __restrict__ shift, float* __restrict__ zc, int colOff) {
    int idx = blockIdx.x * blockDim.x + threadIdx.x;
    if (idx >= N_NODES * H_DIM) return;
    int n = idx >> 6, c = idx & 63;
    zc[(size_t)n * 192 + colOff + c] = zb[idx] * scale[c] + shift[c];
}

// ---------- epilogue ----------

__global__ void pool_k(const float* __restrict__ zc, const int* __restrict__ batch,
                       float* __restrict__ gsum) {
    int idx = blockIdx.x * blockDim.x + threadIdx.x;
    if (idx >= N_NODES * 192) return;
    int n = idx / 192, c = idx - n * 192;
    atomicAdd(&gsum[batch[n] * 192 + c], zc[idx]);
}

__global__ void gc_finalize_k(const float* __restrict__ gsum, const float* __restrict__ cnt,
                              float* __restrict__ gc) {
    int idx = blockIdx.x * blockDim.x + threadIdx.x;
    if (idx >= N_GRAPHS * 192) return;
    int g = idx / 192;
    gc[idx] = gsum[idx] / fmaxf(cnt[g], 1.0f);
}

// one wave per row of 192; in-place L2 normalize
__global__ void l2norm_k(float* __restrict__ data, int rows) {
    int wid = (blockIdx.x * blockDim.x + threadIdx.x) >> 6;
    int lane = threadIdx.x & 63;
    if (wid >= rows) return;
    float* row = data + (size_t)wid * 192;
    float a = row[lane], b = row[lane + 64], c = row[lane + 128];
    float s = a * a + b * b + c * c;
    #pragma unroll
    for (int off = 32; off; off >>= 1) s += __shfl_xor(s, off);
    float inv = 1.0f / fmaxf(sqrtf(s), 1e-12f);
    row[lane] = a * inv; row[lane + 64] = b * inv; row[lane + 128] = c * inv;
}

// ---------- launch ----------

extern "C" void kernel_launch(void* const* d_in, const int* in_sizes, int n_in,
                              void* d_out, int out_size, void* d_ws, size_t ws_size,
                              hipStream_t stream) {
    const float* x     = (const float*)d_in[0];
    const int*   ei    = (const int*)d_in[1];
    const int*   batch = (const int*)d_in[2];
    const float* W[3]     = {(const float*)d_in[3],  (const float*)d_in[7],  (const float*)d_in[11]};
    const float* bias[3]  = {(const float*)d_in[4],  (const float*)d_in[8],  (const float*)d_in[12]};
    const float* gamma[3] = {(const float*)d_in[5],  (const float*)d_in[9],  (const float*)d_in[13]};
    const float* beta[3]  = {(const float*)d_in[6],  (const float*)d_in[10], (const float*)d_in[14]};
    const int* src = ei;
    const int* dst = ei + N_EDGES;

    float* out = (float*)d_out;
    float* zc = out;                                // [N, 192]
    float* gc = out + (size_t)N_NODES * 192;        // [G, 192]

    char* w = (char*)d_ws;
    auto alloc = [&](size_t bytes) -> void* {
        void* p = (void*)w;
        w += (bytes + 255) / 256 * 256;
        return p;
    };
    int*   counts    = (int*)alloc(N_NODES * 4);
    int*   offsets   = (int*)alloc(N_NODES * 4);
    int*   cursor    = (int*)alloc(N_NODES * 4);
    int*   blocksums = (int*)alloc(64 * 4);
    int*   ssrc      = (int*)alloc(N_EDGES * 4);
    float* dinv      = (float*)alloc(N_NODES * 4);
    float* h         = (float*)alloc((size_t)N_NODES * H_DIM * 4);
    float* zb        = (float*)alloc((size_t)N_NODES * H_DIM * 4);
    float* cnt       = (float*)alloc(N_GRAPHS * 4);
    float* gsum      = (float*)alloc(N_GRAPHS * 192 * 4);
    float* bnbuf     = (float*)alloc(4 * 64 * 4);
    float* sums  = bnbuf;
    float* sumsq = bnbuf + 64;
    float* scale = bnbuf + 128;
    float* shift = bnbuf + 192;

    const int nscan = (N_NODES + 1023) / 1024;   // 49

    // preprocessing
    hipMemsetAsync(counts, 0, N_NODES * 4, stream);
    count_edges_k<<<(N_EDGES + 255) / 256, 256, 0, stream>>>(dst, counts);
    scan_block_k<<<nscan, 1024, 0, stream>>>(counts, offsets, blocksums);
    scan_sums_k<<<1, 64, 0, stream>>>(blocksums, nscan);
    finalize_offsets_k<<<(N_NODES + 255) / 256, 256, 0, stream>>>(offsets, cursor, counts, blocksums, dinv);
    fill_csr_k<<<(N_EDGES + 255) / 256, 256, 0, stream>>>(src, dst, cursor, ssrc);
    hipMemsetAsync(cnt, 0, N_GRAPHS * 4, stream);
    graph_cnt_k<<<(N_NODES + 255) / 256, 256, 0, stream>>>(batch, cnt);

    const int waveBlocks = (N_NODES + 3) / 4;    // 4 waves / 256-thread block

    for (int l = 0; l < 3; l++) {
        if (l == 0)
            gemm_k<DIM_IN><<<waveBlocks, 256, 0, stream>>>(x, DIM_IN, W[0], h);
        else
            gemm_k<H_DIM><<<waveBlocks, 256, 0, stream>>>(zc + (l - 1) * 64, 192, W[l], h);
        aggregate_k<<<waveBlocks, 256, 0, stream>>>(h, dinv, offsets, counts, ssrc, bias[l], zb);
        hipMemsetAsync(sums, 0, 2 * 64 * 4, stream);
        bn_stats_k<<<256, 256, 0, stream>>>(zb, sums, sumsq);
        bn_finalize_k<<<1, 64, 0, stream>>>(sums, sumsq, gamma[l], beta[l], scale, shift);
        bn_apply_k<<<(N_NODES * H_DIM + 255) / 256, 256, 0, stream>>>(zb, scale, shift, zc, l * 64);
    }

    hipMemsetAsync(gsum, 0, N_GRAPHS * 192 * 4, stream);
    pool_k<<<(N_NODES * 192 + 255) / 256, 256, 0, stream>>>(zc, batch, gsum);
    gc_finalize_k<<<(N_GRAPHS * 192 + 255) / 256, 256, 0, stream>>>(gsum, cnt, gc);
    l2norm_k<<<(N_NODES + 3) / 4, 256, 0, stream>>>(zc, N_NODES);
    l2norm_k<<<(N_GRAPHS + 3) / 4, 256, 0, stream>>>(gc, N_GRAPHS);
}

// Round 2
// 384.387 us; speedup vs baseline: 1.9304x; 1.9304x over previous
//
#include <hip/hip_runtime.h>
#include <cstdint>
#include <cstddef>

#define N_NODES 50000
#define N_EDGES 800000
#define DIM_IN 128
#define H_DIM 64
#define N_GRAPHS 256
#define EPS_BN 1e-5f

// ---------- preprocessing ----------

__global__ void count_edges_k(const int* __restrict__ dst, int* __restrict__ counts) {
    int e = blockIdx.x * blockDim.x + threadIdx.x;
    if (e < N_EDGES) atomicAdd(&counts[dst[e]], 1);
}

__global__ void scan_block_k(const int* __restrict__ counts, int* __restrict__ offsets,
                             int* __restrict__ blocksums) {
    __shared__ int sh[1024];
    int i = blockIdx.x * 1024 + threadIdx.x;
    int v = (i < N_NODES) ? counts[i] : 0;
    sh[threadIdx.x] = v;
    __syncthreads();
    for (int off = 1; off < 1024; off <<= 1) {
        int t = (threadIdx.x >= off) ? sh[threadIdx.x - off] : 0;
        __syncthreads();
        sh[threadIdx.x] += t;
        __syncthreads();
    }
    if (i < N_NODES) offsets[i] = sh[threadIdx.x] - v;   // exclusive
    if (threadIdx.x == 1023) blocksums[blockIdx.x] = sh[1023];
}

__global__ void scan_sums_k(int* blocksums, int nb) {
    if (threadIdx.x == 0 && blockIdx.x == 0) {
        int run = 0;
        for (int b = 0; b < nb; b++) { int t = blocksums[b]; blocksums[b] = run; run += t; }
    }
}

__global__ void finalize_offsets_k(int* __restrict__ offsets, int* __restrict__ cursor,
                                   const int* __restrict__ counts,
                                   const int* __restrict__ blocksums,
                                   float* __restrict__ dinv) {
    int i = blockIdx.x * blockDim.x + threadIdx.x;
    if (i >= N_NODES) return;
    int o = offsets[i] + blocksums[i >> 10];
    offsets[i] = o;
    cursor[i] = o;
    dinv[i] = rsqrtf((float)(counts[i] + 1));   // +1 self loop, always >= 1
}

__global__ void fill_csr_k(const int* __restrict__ src, const int* __restrict__ dst,
                           int* __restrict__ cursor, int* __restrict__ ssrc) {
    int e = blockIdx.x * blockDim.x + threadIdx.x;
    if (e >= N_EDGES) return;
    int d = dst[e];
    int pos = atomicAdd(&cursor[d], 1);
    ssrc[pos] = src[e];
}

// ---------- per-layer ----------

__device__ inline void fma4(float4& a, float s, const float4& w) {
    a.x = fmaf(s, w.x, a.x);
    a.y = fmaf(s, w.y, a.y);
    a.z = fmaf(s, w.z, a.z);
    a.w = fmaf(s, w.w, a.w);
}

// block = 256 threads, 64 nodes/block. W staged in LDS.
// thread: 4 channels (c4..c4+3) x 4 nodes. Writes h' = (z @ W) * dinv[node].
template<int K>
__global__ __launch_bounds__(256) void gemm_k(const float* __restrict__ Z, int ldz,
                                              const float* __restrict__ W,
                                              const float* __restrict__ dinv,
                                              float* __restrict__ hp) {
    __shared__ float Wl[K * 64];
    for (int i = threadIdx.x * 4; i < K * 64; i += 256 * 4)
        *(float4*)&Wl[i] = *(const float4*)&W[i];
    __syncthreads();

    int c4 = (threadIdx.x & 15) * 4;
    int n0 = blockIdx.x * 64 + (threadIdx.x >> 4) * 4;
    if (n0 >= N_NODES) return;   // 50000 % 4 == 0: rows-of-4 are all-or-nothing

    const float* zr = Z + (size_t)n0 * ldz;
    float4 acc0 = {0,0,0,0}, acc1 = {0,0,0,0}, acc2 = {0,0,0,0}, acc3 = {0,0,0,0};
    #pragma unroll 4
    for (int k = 0; k < K; k += 4) {
        float4 w0 = *(float4*)&Wl[(k + 0) * 64 + c4];
        float4 w1 = *(float4*)&Wl[(k + 1) * 64 + c4];
        float4 w2 = *(float4*)&Wl[(k + 2) * 64 + c4];
        float4 w3 = *(float4*)&Wl[(k + 3) * 64 + c4];
        float4 z0 = *(const float4*)&zr[0 * ldz + k];
        float4 z1 = *(const float4*)&zr[1 * ldz + k];
        float4 z2 = *(const float4*)&zr[2 * ldz + k];
        float4 z3 = *(const float4*)&zr[3 * ldz + k];
        fma4(acc0, z0.x, w0); fma4(acc0, z0.y, w1); fma4(acc0, z0.z, w2); fma4(acc0, z0.w, w3);
        fma4(acc1, z1.x, w0); fma4(acc1, z1.y, w1); fma4(acc1, z1.z, w2); fma4(acc1, z1.w, w3);
        fma4(acc2, z2.x, w0); fma4(acc2, z2.y, w1); fma4(acc2, z2.z, w2); fma4(acc2, z2.w, w3);
        fma4(acc3, z3.x, w0); fma4(acc3, z3.y, w1); fma4(acc3, z3.z, w2); fma4(acc3, z3.w, w3);
    }
    float d0 = dinv[n0], d1 = dinv[n0 + 1], d2 = dinv[n0 + 2], d3 = dinv[n0 + 3];
    acc0.x *= d0; acc0.y *= d0; acc0.z *= d0; acc0.w *= d0;
    acc1.x *= d1; acc1.y *= d1; acc1.z *= d1; acc1.w *= d1;
    acc2.x *= d2; acc2.y *= d2; acc2.z *= d2; acc2.w *= d2;
    acc3.x *= d3; acc3.y *= d3; acc3.z *= d3; acc3.w *= d3;
    *(float4*)&hp[(size_t)(n0 + 0) * 64 + c4] = acc0;
    *(float4*)&hp[(size_t)(n0 + 1) * 64 + c4] = acc1;
    *(float4*)&hp[(size_t)(n0 + 2) * 64 + c4] = acc2;
    *(float4*)&hp[(size_t)(n0 + 3) * 64 + c4] = acc3;
}

// one wave per dst node; 4 lane-groups of 16 handle 4 edges concurrently.
// zb = relu((hp[dst] + sum_e hp[src_e]) * dinv[dst] + bias)
__global__ __launch_bounds__(256) void aggregate_k(const float* __restrict__ hp,
                            const float* __restrict__ dinv,
                            const int* __restrict__ offsets, const int* __restrict__ counts,
                            const int* __restrict__ ssrc, const float* __restrict__ bias,
                            float* __restrict__ zb) {
    int wid = (blockIdx.x * blockDim.x + threadIdx.x) >> 6;
    int lane = threadIdx.x & 63;
    if (wid >= N_NODES) return;
    int g = lane >> 4;
    int c4 = (lane & 15) * 4;
    int s0 = offsets[wid];
    int ce = counts[wid];
    float4 acc = {0, 0, 0, 0};
    for (int e = 0; e < ce; e += 4) {
        int ee = e + g;
        if (ee < ce) {
            int s = ssrc[s0 + ee];
            float4 hv = *(const float4*)&hp[(size_t)s * 64 + c4];
            acc.x += hv.x; acc.y += hv.y; acc.z += hv.z; acc.w += hv.w;
        }
    }
    acc.x += __shfl_xor(acc.x, 16); acc.y += __shfl_xor(acc.y, 16);
    acc.z += __shfl_xor(acc.z, 16); acc.w += __shfl_xor(acc.w, 16);
    acc.x += __shfl_xor(acc.x, 32); acc.y += __shfl_xor(acc.y, 32);
    acc.z += __shfl_xor(acc.z, 32); acc.w += __shfl_xor(acc.w, 32);
    if (g == 0) {
        float4 self = *(const float4*)&hp[(size_t)wid * 64 + c4];
        float di = dinv[wid];
        float4 b4 = *(const float4*)&bias[c4];
        float4 o;
        o.x = fmaxf(fmaf(acc.x + self.x, di, b4.x), 0.f);
        o.y = fmaxf(fmaf(acc.y + self.y, di, b4.y), 0.f);
        o.z = fmaxf(fmaf(acc.z + self.z, di, b4.z), 0.f);
        o.w = fmaxf(fmaf(acc.w + self.w, di, b4.w), 0.f);
        *(float4*)&zb[(size_t)wid * 64 + c4] = o;
    }
}

__global__ void bn_stats_k(const float* __restrict__ zb, float* __restrict__ sums,
                           float* __restrict__ sumsq) {
    int c = threadIdx.x & 63;
    int rowStart = blockIdx.x * 4 + (threadIdx.x >> 6);
    float s = 0.f, q = 0.f;
    for (int r = rowStart; r < N_NODES; r += gridDim.x * 4) {
        float v = zb[(size_t)r * H_DIM + c];
        s += v; q += v * v;
    }
    __shared__ float sh_s[256], sh_q[256];
    sh_s[threadIdx.x] = s; sh_q[threadIdx.x] = q;
    __syncthreads();
    if (threadIdx.x < 64) {
        s = sh_s[threadIdx.x] + sh_s[threadIdx.x + 64] + sh_s[threadIdx.x + 128] + sh_s[threadIdx.x + 192];
        q = sh_q[threadIdx.x] + sh_q[threadIdx.x + 64] + sh_q[threadIdx.x + 128] + sh_q[threadIdx.x + 192];
        atomicAdd(&sums[c], s);
        atomicAdd(&sumsq[c], q);
    }
}

__global__ void bn_finalize_k(const float* __restrict__ sums, const float* __restrict__ sumsq,
                              const float* __restrict__ gamma, const float* __restrict__ beta,
                              float* __restrict__ scale, float* __restrict__ shift) {
    int c = threadIdx.x;
    if (c >= H_DIM) return;
    float mu = sums[c] * (1.0f / N_NODES);
    float var = sumsq[c] * (1.0f / N_NODES) - mu * mu;
    float sc = gamma[c] * rsqrtf(var + EPS_BN);
    scale[c] = sc;
    shift[c] = beta[c] - mu * sc;
}

__global__ void bn_apply_k(const float* __restrict__ zb, const float* __restrict__ scale,
                           const float* __restrict__ shift, float* __restrict__ zc, int colOff) {
    int idx = blockIdx.x * blockDim.x + threadIdx.x;
    if (idx >= N_NODES * H_DIM) return;
    int n = idx >> 6, c = idx & 63;
    zc[(size_t)n * 192 + colOff + c] = zb[idx] * scale[c] + shift[c];
}

// ---------- epilogue ----------

// one block (192 threads) per graph: segmented mean-pool + fused L2 norm.
__global__ __launch_bounds__(192) void pool_k(const float* __restrict__ zc,
                                              const int* __restrict__ batch,
                                              float* __restrict__ gc) {
    int g = blockIdx.x;
    int c = threadIdx.x;
    int lo = 0, hi = N_NODES;
    while (lo < hi) { int mid = (lo + hi) >> 1; if (batch[mid] < g) lo = mid + 1; else hi = mid; }
    int start = lo;
    hi = N_NODES;
    while (lo < hi) { int mid = (lo + hi) >> 1; if (batch[mid] < g + 1) lo = mid + 1; else hi = mid; }
    int end = lo;
    float s = 0.f;
    int n = start;
    for (; n + 4 <= end; n += 4) {
        s += zc[(size_t)(n + 0) * 192 + c];
        s += zc[(size_t)(n + 1) * 192 + c];
        s += zc[(size_t)(n + 2) * 192 + c];
        s += zc[(size_t)(n + 3) * 192 + c];
    }
    for (; n < end; n++) s += zc[(size_t)n * 192 + c];
    s = s / fmaxf((float)(end - start), 1.0f);
    __shared__ float part[3];
    float q = s * s;
    #pragma unroll
    for (int off = 32; off; off >>= 1) q += __shfl_xor(q, off);
    if ((threadIdx.x & 63) == 0) part[threadIdx.x >> 6] = q;
    __syncthreads();
    float inv = 1.0f / fmaxf(sqrtf(part[0] + part[1] + part[2]), 1e-12f);
    gc[(size_t)g * 192 + c] = s * inv;
}

// one wave per row of 192; in-place L2 normalize
__global__ void l2norm_k(float* __restrict__ data, int rows) {
    int wid = (blockIdx.x * blockDim.x + threadIdx.x) >> 6;
    int lane = threadIdx.x & 63;
    if (wid >= rows) return;
    float* row = data + (size_t)wid * 192;
    float a = row[lane], b = row[lane + 64], c = row[lane + 128];
    float s = a * a + b * b + c * c;
    #pragma unroll
    for (int off = 32; off; off >>= 1) s += __shfl_xor(s, off);
    float inv = 1.0f / fmaxf(sqrtf(s), 1e-12f);
    row[lane] = a * inv; row[lane + 64] = b * inv; row[lane + 128] = c * inv;
}

// ---------- launch ----------

extern "C" void kernel_launch(void* const* d_in, const int* in_sizes, int n_in,
                              void* d_out, int out_size, void* d_ws, size_t ws_size,
                              hipStream_t stream) {
    const float* x     = (const float*)d_in[0];
    const int*   ei    = (const int*)d_in[1];
    const int*   batch = (const int*)d_in[2];
    const float* W[3]     = {(const float*)d_in[3],  (const float*)d_in[7],  (const float*)d_in[11]};
    const float* bias[3]  = {(const float*)d_in[4],  (const float*)d_in[8],  (const float*)d_in[12]};
    const float* gamma[3] = {(const float*)d_in[5],  (const float*)d_in[9],  (const float*)d_in[13]};
    const float* beta[3]  = {(const float*)d_in[6],  (const float*)d_in[10], (const float*)d_in[14]};
    const int* src = ei;
    const int* dst = ei + N_EDGES;

    float* out = (float*)d_out;
    float* zc = out;                                // [N, 192]
    float* gc = out + (size_t)N_NODES * 192;        // [G, 192]

    char* w = (char*)d_ws;
    auto alloc = [&](size_t bytes) -> void* {
        void* p = (void*)w;
        w += (bytes + 255) / 256 * 256;
        return p;
    };
    int*   counts    = (int*)alloc(N_NODES * 4);
    int*   offsets   = (int*)alloc(N_NODES * 4);
    int*   cursor    = (int*)alloc(N_NODES * 4);
    int*   blocksums = (int*)alloc(64 * 4);
    int*   ssrc      = (int*)alloc(N_EDGES * 4);
    float* dinv      = (float*)alloc(N_NODES * 4);
    float* hp        = (float*)alloc((size_t)N_NODES * H_DIM * 4);
    float* zb        = (float*)alloc((size_t)N_NODES * H_DIM * 4);
    float* bnbuf     = (float*)alloc(4 * 64 * 4);
    float* sums  = bnbuf;
    float* sumsq = bnbuf + 64;
    float* scale = bnbuf + 128;
    float* shift = bnbuf + 192;

    const int nscan = (N_NODES + 1023) / 1024;   // 49

    hipMemsetAsync(counts, 0, N_NODES * 4, stream);
    count_edges_k<<<(N_EDGES + 255) / 256, 256, 0, stream>>>(dst, counts);
    scan_block_k<<<nscan, 1024, 0, stream>>>(counts, offsets, blocksums);
    scan_sums_k<<<1, 64, 0, stream>>>(blocksums, nscan);
    finalize_offsets_k<<<(N_NODES + 255) / 256, 256, 0, stream>>>(offsets, cursor, counts, blocksums, dinv);
    fill_csr_k<<<(N_EDGES + 255) / 256, 256, 0, stream>>>(src, dst, cursor, ssrc);

    const int gemmBlocks = (N_NODES + 63) / 64;   // 782
    const int waveBlocks = (N_NODES + 3) / 4;     // 12500

    for (int l = 0; l < 3; l++) {
        if (l == 0)
            gemm_k<DIM_IN><<<gemmBlocks, 256, 0, stream>>>(x, DIM_IN, W[0], dinv, hp);
        else
            gemm_k<H_DIM><<<gemmBlocks, 256, 0, stream>>>(zc + (l - 1) * 64, 192, W[l], dinv, hp);
        aggregate_k<<<waveBlocks, 256, 0, stream>>>(hp, dinv, offsets, counts, ssrc, bias[l], zb);
        hipMemsetAsync(sums, 0, 2 * 64 * 4, stream);
        bn_stats_k<<<256, 256, 0, stream>>>(zb, sums, sumsq);
        bn_finalize_k<<<1, 64, 0, stream>>>(sums, sumsq, gamma[l], beta[l], scale, shift);
        bn_apply_k<<<(N_NODES * H_DIM + 255) / 256, 256, 0, stream>>>(zb, scale, shift, zc, l * 64);
    }

    pool_k<<<N_GRAPHS, 192, 0, stream>>>(zc, batch, gc);
    l2norm_k<<<(N_NODES + 3) / 4, 256, 0, stream>>>(zc, N_NODES);
    l2norm_k<<<(N_GRAPHS + 3) / 4, 256, 0, stream>>>(gc, N_GRAPHS);
}

// Round 3
// 334.108 us; speedup vs baseline: 2.2209x; 1.1505x over previous
//
#include <hip/hip_runtime.h>
#include <hip/hip_fp16.h>
#include <cstdint>
#include <cstddef>

#define N_NODES 50000
#define N_EDGES 800000
#define DIM_IN 128
#define H_DIM 64
#define N_GRAPHS 256
#define EPS_BN 1e-5f
#define GEMM0_BLOCKS 782   // ceil(50000/64)
#define FILL_BLOCKS 3125   // 800000/256

struct __align__(16) h8 { __half2 a, b, c, d; };
struct __align__(8)  h4 { __half2 a, b; };

__device__ inline void fma4(float4& a, float s, const float4& w) {
    a.x = fmaf(s, w.x, a.x);
    a.y = fmaf(s, w.y, a.y);
    a.z = fmaf(s, w.z, a.z);
    a.w = fmaf(s, w.w, a.w);
}

__device__ inline h4 pack_h4(float4 v) {
    h4 r;
    r.a = __float22half2_rn(make_float2(v.x, v.y));
    r.b = __float22half2_rn(make_float2(v.z, v.w));
    return r;
}

// ---------- preprocessing ----------

__global__ void count_edges_k(const int* __restrict__ dst, int* __restrict__ counts) {
    int e4 = (blockIdx.x * blockDim.x + threadIdx.x) * 4;
    if (e4 >= N_EDGES) return;
    int4 d = *(const int4*)&dst[e4];
    atomicAdd(&counts[d.x], 1);
    atomicAdd(&counts[d.y], 1);
    atomicAdd(&counts[d.z], 1);
    atomicAdd(&counts[d.w], 1);
}

__global__ void scan_block_k(const int* __restrict__ counts, int* __restrict__ offsets,
                             int* __restrict__ blocksums) {
    __shared__ int sh[1024];
    int i = blockIdx.x * 1024 + threadIdx.x;
    int v = (i < N_NODES) ? counts[i] : 0;
    sh[threadIdx.x] = v;
    __syncthreads();
    for (int off = 1; off < 1024; off <<= 1) {
        int t = (threadIdx.x >= off) ? sh[threadIdx.x - off] : 0;
        __syncthreads();
        sh[threadIdx.x] += t;
        __syncthreads();
    }
    if (i < N_NODES) offsets[i] = sh[threadIdx.x] - v;   // exclusive
    if (threadIdx.x == 1023) blocksums[blockIdx.x] = sh[1023];
}

__global__ void scan_sums_k(int* blocksums, int nb) {
    if (threadIdx.x == 0 && blockIdx.x == 0) {
        int run = 0;
        for (int b = 0; b < nb; b++) { int t = blocksums[b]; blocksums[b] = run; run += t; }
    }
}

__global__ void finalize_offsets_k(int* __restrict__ offsets, int* __restrict__ cursor,
                                   const int* __restrict__ counts,
                                   const int* __restrict__ blocksums,
                                   float* __restrict__ dinv) {
    int i = blockIdx.x * blockDim.x + threadIdx.x;
    if (i >= N_NODES) return;
    int o = offsets[i] + blocksums[i >> 10];
    offsets[i] = o;
    cursor[i] = o;
    dinv[i] = rsqrtf((float)(counts[i] + 1));   // +1 self loop
}

// ---------- fused: gemm layer 0 (fp32 in, fp16*dinv out) + CSR fill ----------

__global__ __launch_bounds__(256) void gemm0_fill_k(
        const float* __restrict__ X, const float* __restrict__ W,
        const float* __restrict__ dinv, __half* __restrict__ hp,
        const int* __restrict__ src, const int* __restrict__ dst,
        int* __restrict__ cursor, unsigned short* __restrict__ ssrc) {
    __shared__ float Wl[DIM_IN * 64];
    if (blockIdx.x < GEMM0_BLOCKS) {
        for (int i = threadIdx.x * 4; i < DIM_IN * 64; i += 256 * 4)
            *(float4*)&Wl[i] = *(const float4*)&W[i];
        __syncthreads();
        int c4 = (threadIdx.x & 15) * 4;
        int n0 = blockIdx.x * 64 + (threadIdx.x >> 4) * 4;
        if (n0 >= N_NODES) return;
        const float* zr = X + (size_t)n0 * DIM_IN;
        float4 acc0 = {0,0,0,0}, acc1 = {0,0,0,0}, acc2 = {0,0,0,0}, acc3 = {0,0,0,0};
        #pragma unroll 4
        for (int k = 0; k < DIM_IN; k += 4) {
            float4 w0 = *(float4*)&Wl[(k + 0) * 64 + c4];
            float4 w1 = *(float4*)&Wl[(k + 1) * 64 + c4];
            float4 w2 = *(float4*)&Wl[(k + 2) * 64 + c4];
            float4 w3 = *(float4*)&Wl[(k + 3) * 64 + c4];
            float4 z0 = *(const float4*)&zr[0 * DIM_IN + k];
            float4 z1 = *(const float4*)&zr[1 * DIM_IN + k];
            float4 z2 = *(const float4*)&zr[2 * DIM_IN + k];
            float4 z3 = *(const float4*)&zr[3 * DIM_IN + k];
            fma4(acc0, z0.x, w0); fma4(acc0, z0.y, w1); fma4(acc0, z0.z, w2); fma4(acc0, z0.w, w3);
            fma4(acc1, z1.x, w0); fma4(acc1, z1.y, w1); fma4(acc1, z1.z, w2); fma4(acc1, z1.w, w3);
            fma4(acc2, z2.x, w0); fma4(acc2, z2.y, w1); fma4(acc2, z2.z, w2); fma4(acc2, z2.w, w3);
            fma4(acc3, z3.x, w0); fma4(acc3, z3.y, w1); fma4(acc3, z3.z, w2); fma4(acc3, z3.w, w3);
        }
        float d0 = dinv[n0], d1 = dinv[n0 + 1], d2 = dinv[n0 + 2], d3 = dinv[n0 + 3];
        acc0.x *= d0; acc0.y *= d0; acc0.z *= d0; acc0.w *= d0;
        acc1.x *= d1; acc1.y *= d1; acc1.z *= d1; acc1.w *= d1;
        acc2.x *= d2; acc2.y *= d2; acc2.z *= d2; acc2.w *= d2;
        acc3.x *= d3; acc3.y *= d3; acc3.z *= d3; acc3.w *= d3;
        *(h4*)&hp[(size_t)(n0 + 0) * 64 + c4] = pack_h4(acc0);
        *(h4*)&hp[(size_t)(n0 + 1) * 64 + c4] = pack_h4(acc1);
        *(h4*)&hp[(size_t)(n0 + 2) * 64 + c4] = pack_h4(acc2);
        *(h4*)&hp[(size_t)(n0 + 3) * 64 + c4] = pack_h4(acc3);
    } else {
        int e = (blockIdx.x - GEMM0_BLOCKS) * 256 + threadIdx.x;
        if (e >= N_EDGES) return;
        int d = dst[e];
        int pos = atomicAdd(&cursor[d], 1);
        ssrc[pos] = (unsigned short)src[e];
    }
}

// ---------- gemm layers 1/2: fp16 zb input + BN affine, fp16*dinv out ----------

__global__ __launch_bounds__(256) void gemm_h_k(
        const __half* __restrict__ Z, const float* __restrict__ W,
        const float* __restrict__ scale, const float* __restrict__ shift,
        const float* __restrict__ dinv, __half* __restrict__ hp) {
    __shared__ float Wl[H_DIM * 64];
    __shared__ float scl[64], shl[64];
    for (int i = threadIdx.x * 4; i < H_DIM * 64; i += 256 * 4)
        *(float4*)&Wl[i] = *(const float4*)&W[i];
    if (threadIdx.x < 64) { scl[threadIdx.x] = scale[threadIdx.x]; shl[threadIdx.x] = shift[threadIdx.x]; }
    __syncthreads();
    int c4 = (threadIdx.x & 15) * 4;
    int n0 = blockIdx.x * 64 + (threadIdx.x >> 4) * 4;
    if (n0 >= N_NODES) return;
    float4 acc0 = {0,0,0,0}, acc1 = {0,0,0,0}, acc2 = {0,0,0,0}, acc3 = {0,0,0,0};
    #pragma unroll 4
    for (int k = 0; k < H_DIM; k += 4) {
        float4 w0 = *(float4*)&Wl[(k + 0) * 64 + c4];
        float4 w1 = *(float4*)&Wl[(k + 1) * 64 + c4];
        float4 w2 = *(float4*)&Wl[(k + 2) * 64 + c4];
        float4 w3 = *(float4*)&Wl[(k + 3) * 64 + c4];
        float4 s4 = *(float4*)&scl[k];
        float4 f4 = *(float4*)&shl[k];
        #define DO_NODE(ACC, I)                                                        \
        {   h4 r = *(const h4*)&Z[(size_t)(n0 + I) * 64 + k];                          \
            float2 p = __half22float2(r.a), q = __half22float2(r.b);                   \
            float z0 = fmaf(p.x, s4.x, f4.x), z1 = fmaf(p.y, s4.y, f4.y);              \
            float z2 = fmaf(q.x, s4.z, f4.z), z3 = fmaf(q.y, s4.w, f4.w);              \
            fma4(ACC, z0, w0); fma4(ACC, z1, w1); fma4(ACC, z2, w2); fma4(ACC, z3, w3); }
        DO_NODE(acc0, 0) DO_NODE(acc1, 1) DO_NODE(acc2, 2) DO_NODE(acc3, 3)
        #undef DO_NODE
    }
    float d0 = dinv[n0], d1 = dinv[n0 + 1], d2 = dinv[n0 + 2], d3 = dinv[n0 + 3];
    acc0.x *= d0; acc0.y *= d0; acc0.z *= d0; acc0.w *= d0;
    acc1.x *= d1; acc1.y *= d1; acc1.z *= d1; acc1.w *= d1;
    acc2.x *= d2; acc2.y *= d2; acc2.z *= d2; acc2.w *= d2;
    acc3.x *= d3; acc3.y *= d3; acc3.z *= d3; acc3.w *= d3;
    *(h4*)&hp[(size_t)(n0 + 0) * 64 + c4] = pack_h4(acc0);
    *(h4*)&hp[(size_t)(n0 + 1) * 64 + c4] = pack_h4(acc1);
    *(h4*)&hp[(size_t)(n0 + 2) * 64 + c4] = pack_h4(acc2);
    *(h4*)&hp[(size_t)(n0 + 3) * 64 + c4] = pack_h4(acc3);
}

// ---------- aggregate + relu + fused BN partial stats ----------
// wave per node; 8 lane-groups of 8 handle 8 edges in flight; lane covers 8 channels (16B).
__global__ __launch_bounds__(256) void aggregate_k(
        const __half* __restrict__ hp, const float* __restrict__ dinv,
        const int* __restrict__ offsets, const int* __restrict__ counts,
        const unsigned short* __restrict__ ssrc, const float* __restrict__ bias,
        __half* __restrict__ zb, float* __restrict__ slots) {
    int wid = (blockIdx.x * blockDim.x + threadIdx.x) >> 6;   // node (grid exact)
    int lane = threadIdx.x & 63;
    int g = lane >> 3;            // edge sub-slot 0..7
    int c8 = (lane & 7) * 8;      // channel base
    float a0=0,a1=0,a2=0,a3=0,a4=0,a5=0,a6=0,a7=0;
    int s0 = offsets[wid];
    int ce = counts[wid];
    for (int e = g; e < ce; e += 8) {
        int s = ssrc[s0 + e];
        h8 v = *(const h8*)(hp + (size_t)s * 64 + c8);
        float2 f0 = __half22float2(v.a), f1 = __half22float2(v.b);
        float2 f2 = __half22float2(v.c), f3 = __half22float2(v.d);
        a0 += f0.x; a1 += f0.y; a2 += f1.x; a3 += f1.y;
        a4 += f2.x; a5 += f2.y; a6 += f3.x; a7 += f3.y;
    }
    #define RED(A) A += __shfl_xor(A, 8); A += __shfl_xor(A, 16); A += __shfl_xor(A, 32);
    RED(a0) RED(a1) RED(a2) RED(a3) RED(a4) RED(a5) RED(a6) RED(a7)
    #undef RED
    __shared__ float lds_s[4][64];
    __shared__ float lds_q[4][64];
    int w = threadIdx.x >> 6;
    if (g == 0) {
        h8 sv = *(const h8*)(hp + (size_t)wid * 64 + c8);
        float2 f0 = __half22float2(sv.a), f1 = __half22float2(sv.b);
        float2 f2 = __half22float2(sv.c), f3 = __half22float2(sv.d);
        float di = dinv[wid];
        float4 b0 = *(const float4*)&bias[c8];
        float4 b1 = *(const float4*)&bias[c8 + 4];
        float o0 = fmaxf(fmaf(a0 + f0.x, di, b0.x), 0.f);
        float o1 = fmaxf(fmaf(a1 + f0.y, di, b0.y), 0.f);
        float o2 = fmaxf(fmaf(a2 + f1.x, di, b0.z), 0.f);
        float o3 = fmaxf(fmaf(a3 + f1.y, di, b0.w), 0.f);
        float o4 = fmaxf(fmaf(a4 + f2.x, di, b1.x), 0.f);
        float o5 = fmaxf(fmaf(a5 + f2.y, di, b1.y), 0.f);
        float o6 = fmaxf(fmaf(a6 + f3.x, di, b1.z), 0.f);
        float o7 = fmaxf(fmaf(a7 + f3.y, di, b1.w), 0.f);
        h8 ov;
        ov.a = __float22half2_rn(make_float2(o0, o1));
        ov.b = __float22half2_rn(make_float2(o2, o3));
        ov.c = __float22half2_rn(make_float2(o4, o5));
        ov.d = __float22half2_rn(make_float2(o6, o7));
        *(h8*)(zb + (size_t)wid * 64 + c8) = ov;
        lds_s[w][c8+0]=o0; lds_s[w][c8+1]=o1; lds_s[w][c8+2]=o2; lds_s[w][c8+3]=o3;
        lds_s[w][c8+4]=o4; lds_s[w][c8+5]=o5; lds_s[w][c8+6]=o6; lds_s[w][c8+7]=o7;
        lds_q[w][c8+0]=o0*o0; lds_q[w][c8+1]=o1*o1; lds_q[w][c8+2]=o2*o2; lds_q[w][c8+3]=o3*o3;
        lds_q[w][c8+4]=o4*o4; lds_q[w][c8+5]=o5*o5; lds_q[w][c8+6]=o6*o6; lds_q[w][c8+7]=o7*o7;
    }
    __syncthreads();
    int c = threadIdx.x & 63;
    if (threadIdx.x < 64) {
        float t = lds_s[0][c] + lds_s[1][c] + lds_s[2][c] + lds_s[3][c];
        atomicAdd(&slots[(blockIdx.x & 63) * 128 + c], t);
    } else if (threadIdx.x < 128) {
        float t = lds_q[0][c] + lds_q[1][c] + lds_q[2][c] + lds_q[3][c];
        atomicAdd(&slots[(blockIdx.x & 63) * 128 + 64 + c], t);
    }
}

// reduce the 64 stat slots -> scale/shift, then re-zero slots for next layer
__global__ void bn_finalize_k(float* __restrict__ slots,
                              const float* __restrict__ gamma, const float* __restrict__ beta,
                              float* __restrict__ scale, float* __restrict__ shift) {
    __shared__ float red[128];
    int c = threadIdx.x;   // 0..127
    float s = 0.f;
    for (int b = 0; b < 64; b++) s += slots[b * 128 + c];
    red[c] = s;
    __syncthreads();
    if (c < 64) {
        float mu = red[c] * (1.0f / N_NODES);
        float var = red[c + 64] * (1.0f / N_NODES) - mu * mu;
        float k = gamma[c] * rsqrtf(var + EPS_BN);
        scale[c] = k;
        shift[c] = beta[c] - mu * k;
    }
    for (int i = c; i < 64 * 128; i += 128) slots[i] = 0.f;
}

// ---------- epilogue ----------

// one block (192 threads) per graph: mean-pool of z (=zb*scale+shift) + fused L2 norm
__global__ __launch_bounds__(192) void pool_k(
        const __half* __restrict__ zb0, const __half* __restrict__ zb1,
        const __half* __restrict__ zb2,
        const float* __restrict__ scaleAll, const float* __restrict__ shiftAll,
        const int* __restrict__ batch, float* __restrict__ gc) {
    int g = blockIdx.x;
    int t = threadIdx.x;            // 0..191: layer = t/64, ch = t%64
    const __half* zb = (t < 64) ? zb0 : (t < 128) ? zb1 : zb2;
    int ch = t & 63;
    int lo = 0, hi = N_NODES;
    while (lo < hi) { int mid = (lo + hi) >> 1; if (batch[mid] < g) lo = mid + 1; else hi = mid; }
    int start = lo;
    hi = N_NODES;
    while (lo < hi) { int mid = (lo + hi) >> 1; if (batch[mid] < g + 1) lo = mid + 1; else hi = mid; }
    int end = lo;
    float s = 0.f;
    for (int n = start; n < end; n++) s += __half2float(zb[(size_t)n * 64 + ch]);
    float cnt = fmaxf((float)(end - start), 1.0f);
    // mean(z) = scale*mean(zb) + shift  (affine is linear; shift only if segment nonempty)
    float m = (end > start) ? (scaleAll[t] * (s / cnt) + shiftAll[t]) : 0.f;
    __shared__ float part[3];
    float q = m * m;
    #pragma unroll
    for (int off = 32; off; off >>= 1) q += __shfl_xor(q, off);
    if ((t & 63) == 0) part[t >> 6] = q;
    __syncthreads();
    float inv = 1.0f / fmaxf(sqrtf(part[0] + part[1] + part[2]), 1e-12f);
    gc[(size_t)g * 192 + t] = m * inv;
}

// one wave per node: z = zb*scale+shift for 3 layers, L2 normalize, write zc fp32
__global__ __launch_bounds__(256) void l2norm_zc_k(
        const __half* __restrict__ zb0, const __half* __restrict__ zb1,
        const __half* __restrict__ zb2,
        const float* __restrict__ scaleAll, const float* __restrict__ shiftAll,
        float* __restrict__ zc) {
    int wid = (blockIdx.x * blockDim.x + threadIdx.x) >> 6;
    int lane = threadIdx.x & 63;
    float a = fmaf(__half2float(zb0[(size_t)wid * 64 + lane]), scaleAll[lane],       shiftAll[lane]);
    float b = fmaf(__half2float(zb1[(size_t)wid * 64 + lane]), scaleAll[64 + lane],  shiftAll[64 + lane]);
    float c = fmaf(__half2float(zb2[(size_t)wid * 64 + lane]), scaleAll[128 + lane], shiftAll[128 + lane]);
    float s = a * a + b * b + c * c;
    #pragma unroll
    for (int off = 32; off; off >>= 1) s += __shfl_xor(s, off);
    float inv = 1.0f / fmaxf(sqrtf(s), 1e-12f);
    float* row = zc + (size_t)wid * 192;
    row[lane] = a * inv; row[lane + 64] = b * inv; row[lane + 128] = c * inv;
}

// ---------- launch ----------

extern "C" void kernel_launch(void* const* d_in, const int* in_sizes, int n_in,
                              void* d_out, int out_size, void* d_ws, size_t ws_size,
                              hipStream_t stream) {
    const float* x     = (const float*)d_in[0];
    const int*   ei    = (const int*)d_in[1];
    const int*   batch = (const int*)d_in[2];
    const float* W[3]     = {(const float*)d_in[3],  (const float*)d_in[7],  (const float*)d_in[11]};
    const float* bias[3]  = {(const float*)d_in[4],  (const float*)d_in[8],  (const float*)d_in[12]};
    const float* gamma[3] = {(const float*)d_in[5],  (const float*)d_in[9],  (const float*)d_in[13]};
    const float* beta[3]  = {(const float*)d_in[6],  (const float*)d_in[10], (const float*)d_in[14]};
    const int* src = ei;
    const int* dst = ei + N_EDGES;

    float* out = (float*)d_out;
    float* zc = out;                                // [N, 192]
    float* gc = out + (size_t)N_NODES * 192;        // [G, 192]

    char* w = (char*)d_ws;
    auto alloc = [&](size_t bytes) -> void* {
        void* p = (void*)w;
        w += (bytes + 255) / 256 * 256;
        return p;
    };
    int*            counts    = (int*)alloc(N_NODES * 4);
    int*            offsets   = (int*)alloc(N_NODES * 4);
    int*            cursor    = (int*)alloc(N_NODES * 4);
    int*            blocksums = (int*)alloc(64 * 4);
    float*          dinv      = (float*)alloc(N_NODES * 4);
    unsigned short* ssrc      = (unsigned short*)alloc(N_EDGES * 2);
    __half*         hp        = (__half*)alloc((size_t)N_NODES * 64 * 2);
    __half*         zb[3];
    zb[0] = (__half*)alloc((size_t)N_NODES * 64 * 2);
    zb[1] = (__half*)alloc((size_t)N_NODES * 64 * 2);
    zb[2] = (__half*)alloc((size_t)N_NODES * 64 * 2);
    float*          slots     = (float*)alloc(64 * 128 * 4);
    float*          scaleAll  = (float*)alloc(192 * 4);
    float*          shiftAll  = (float*)alloc(192 * 4);

    const int nscan = (N_NODES + 1023) / 1024;   // 49

    hipMemsetAsync(counts, 0, N_NODES * 4, stream);
    hipMemsetAsync(slots, 0, 64 * 128 * 4, stream);
    count_edges_k<<<(N_EDGES / 4 + 255) / 256, 256, 0, stream>>>(dst, counts);
    scan_block_k<<<nscan, 1024, 0, stream>>>(counts, offsets, blocksums);
    scan_sums_k<<<1, 64, 0, stream>>>(blocksums, nscan);
    finalize_offsets_k<<<(N_NODES + 255) / 256, 256, 0, stream>>>(offsets, cursor, counts, blocksums, dinv);

    gemm0_fill_k<<<GEMM0_BLOCKS + FILL_BLOCKS, 256, 0, stream>>>(x, W[0], dinv, hp,
                                                                 src, dst, cursor, ssrc);

    const int aggBlocks = N_NODES / 4;   // 12500, exact

    for (int l = 0; l < 3; l++) {
        if (l > 0)
            gemm_h_k<<<GEMM0_BLOCKS, 256, 0, stream>>>(zb[l - 1], W[l],
                                                       scaleAll + (l - 1) * 64, shiftAll + (l - 1) * 64,
                                                       dinv, hp);
        aggregate_k<<<aggBlocks, 256, 0, stream>>>(hp, dinv, offsets, counts, ssrc,
                                                   bias[l], zb[l], slots);
        bn_finalize_k<<<1, 128, 0, stream>>>(slots, gamma[l], beta[l],
                                             scaleAll + l * 64, shiftAll + l * 64);
    }

    pool_k<<<N_GRAPHS, 192, 0, stream>>>(zb[0], zb[1], zb[2], scaleAll, shiftAll, batch, gc);
    l2norm_zc_k<<<N_NODES / 4, 256, 0, stream>>>(zb[0], zb[1], zb[2], scaleAll, shiftAll, zc);
}

// Round 4
// 279.426 us; speedup vs baseline: 2.6556x; 1.1957x over previous
//
#include <hip/hip_runtime.h>
#include <hip/hip_fp16.h>
#include <cstdint>
#include <cstddef>

#define N_NODES 50000
#define N_EDGES 800000
#define DIM_IN 128
#define H_DIM 64
#define N_GRAPHS 256
#define EPS_BN 1e-5f
#define GEMM0_BLOCKS 782   // ceil(50000/64)
#define FILL_BLOCKS 3125   // 800000/256

struct __align__(16) h8 { __half2 a, b, c, d; };
struct __align__(8)  h4 { __half2 a, b; };

__device__ inline void fma4(float4& a, float s, const float4& w) {
    a.x = fmaf(s, w.x, a.x);
    a.y = fmaf(s, w.y, a.y);
    a.z = fmaf(s, w.z, a.z);
    a.w = fmaf(s, w.w, a.w);
}

__device__ inline h4 pack_h4(float4 v) {
    h4 r;
    r.a = __float22half2_rn(make_float2(v.x, v.y));
    r.b = __float22half2_rn(make_float2(v.z, v.w));
    return r;
}

// ---------- preprocessing ----------

__global__ void count_edges_k(const int* __restrict__ dst, int* __restrict__ counts) {
    int e4 = (blockIdx.x * blockDim.x + threadIdx.x) * 4;
    if (e4 >= N_EDGES) return;
    int4 d = *(const int4*)&dst[e4];
    atomicAdd(&counts[d.x], 1);
    atomicAdd(&counts[d.y], 1);
    atomicAdd(&counts[d.z], 1);
    atomicAdd(&counts[d.w], 1);
}

__global__ void scan_block_k(const int* __restrict__ counts, int* __restrict__ offsets,
                             int* __restrict__ blocksums) {
    __shared__ int sh[1024];
    int i = blockIdx.x * 1024 + threadIdx.x;
    int v = (i < N_NODES) ? counts[i] : 0;
    sh[threadIdx.x] = v;
    __syncthreads();
    for (int off = 1; off < 1024; off <<= 1) {
        int t = (threadIdx.x >= off) ? sh[threadIdx.x - off] : 0;
        __syncthreads();
        sh[threadIdx.x] += t;
        __syncthreads();
    }
    if (i < N_NODES) offsets[i] = sh[threadIdx.x] - v;   // exclusive
    if (threadIdx.x == 1023) blocksums[blockIdx.x] = sh[1023];
}

__global__ void scan_sums_k(int* blocksums, int nb) {
    if (threadIdx.x == 0 && blockIdx.x == 0) {
        int run = 0;
        for (int b = 0; b < nb; b++) { int t = blocksums[b]; blocksums[b] = run; run += t; }
    }
}

__global__ void finalize_offsets_k(int* __restrict__ offsets, int* __restrict__ cursor,
                                   const int* __restrict__ counts,
                                   const int* __restrict__ blocksums,
                                   float* __restrict__ dinv) {
    int i = blockIdx.x * blockDim.x + threadIdx.x;
    if (i >= N_NODES) return;
    int o = offsets[i] + blocksums[i >> 10];
    offsets[i] = o;
    cursor[i] = o;
    dinv[i] = rsqrtf((float)(counts[i] + 1));   // +1 self loop
}

// ---------- fused: gemm layer 0 (fp32 in, fp16*dinv out) + CSR fill ----------

__global__ __launch_bounds__(256) void gemm0_fill_k(
        const float* __restrict__ X, const float* __restrict__ W,
        const float* __restrict__ dinv, __half* __restrict__ hp,
        const int* __restrict__ src, const int* __restrict__ dst,
        int* __restrict__ cursor, unsigned short* __restrict__ ssrc) {
    __shared__ float Wl[DIM_IN * 64];
    if (blockIdx.x < GEMM0_BLOCKS) {
        for (int i = threadIdx.x * 4; i < DIM_IN * 64; i += 256 * 4)
            *(float4*)&Wl[i] = *(const float4*)&W[i];
        __syncthreads();
        int c4 = (threadIdx.x & 15) * 4;
        int n0 = blockIdx.x * 64 + (threadIdx.x >> 4) * 4;
        if (n0 >= N_NODES) return;
        const float* zr = X + (size_t)n0 * DIM_IN;
        float4 acc0 = {0,0,0,0}, acc1 = {0,0,0,0}, acc2 = {0,0,0,0}, acc3 = {0,0,0,0};
        #pragma unroll 4
        for (int k = 0; k < DIM_IN; k += 4) {
            float4 w0 = *(float4*)&Wl[(k + 0) * 64 + c4];
            float4 w1 = *(float4*)&Wl[(k + 1) * 64 + c4];
            float4 w2 = *(float4*)&Wl[(k + 2) * 64 + c4];
            float4 w3 = *(float4*)&Wl[(k + 3) * 64 + c4];
            float4 z0 = *(const float4*)&zr[0 * DIM_IN + k];
            float4 z1 = *(const float4*)&zr[1 * DIM_IN + k];
            float4 z2 = *(const float4*)&zr[2 * DIM_IN + k];
            float4 z3 = *(const float4*)&zr[3 * DIM_IN + k];
            fma4(acc0, z0.x, w0); fma4(acc0, z0.y, w1); fma4(acc0, z0.z, w2); fma4(acc0, z0.w, w3);
            fma4(acc1, z1.x, w0); fma4(acc1, z1.y, w1); fma4(acc1, z1.z, w2); fma4(acc1, z1.w, w3);
            fma4(acc2, z2.x, w0); fma4(acc2, z2.y, w1); fma4(acc2, z2.z, w2); fma4(acc2, z2.w, w3);
            fma4(acc3, z3.x, w0); fma4(acc3, z3.y, w1); fma4(acc3, z3.z, w2); fma4(acc3, z3.w, w3);
        }
        float d0 = dinv[n0], d1 = dinv[n0 + 1], d2 = dinv[n0 + 2], d3 = dinv[n0 + 3];
        acc0.x *= d0; acc0.y *= d0; acc0.z *= d0; acc0.w *= d0;
        acc1.x *= d1; acc1.y *= d1; acc1.z *= d1; acc1.w *= d1;
        acc2.x *= d2; acc2.y *= d2; acc2.z *= d2; acc2.w *= d2;
        acc3.x *= d3; acc3.y *= d3; acc3.z *= d3; acc3.w *= d3;
        *(h4*)&hp[(size_t)(n0 + 0) * 64 + c4] = pack_h4(acc0);
        *(h4*)&hp[(size_t)(n0 + 1) * 64 + c4] = pack_h4(acc1);
        *(h4*)&hp[(size_t)(n0 + 2) * 64 + c4] = pack_h4(acc2);
        *(h4*)&hp[(size_t)(n0 + 3) * 64 + c4] = pack_h4(acc3);
    } else {
        int e = (blockIdx.x - GEMM0_BLOCKS) * 256 + threadIdx.x;
        if (e >= N_EDGES) return;
        int d = dst[e];
        int pos = atomicAdd(&cursor[d], 1);
        ssrc[pos] = (unsigned short)src[e];
    }
}

// ---------- gemm layers 1/2: fp16 zb input + BN affine, fp16*dinv out ----------

__global__ __launch_bounds__(256) void gemm_h_k(
        const __half* __restrict__ Z, const float* __restrict__ W,
        const float* __restrict__ scale, const float* __restrict__ shift,
        const float* __restrict__ dinv, __half* __restrict__ hp) {
    __shared__ float Wl[H_DIM * 64];
    __shared__ float scl[64], shl[64];
    for (int i = threadIdx.x * 4; i < H_DIM * 64; i += 256 * 4)
        *(float4*)&Wl[i] = *(const float4*)&W[i];
    if (threadIdx.x < 64) { scl[threadIdx.x] = scale[threadIdx.x]; shl[threadIdx.x] = shift[threadIdx.x]; }
    __syncthreads();
    int c4 = (threadIdx.x & 15) * 4;
    int n0 = blockIdx.x * 64 + (threadIdx.x >> 4) * 4;
    if (n0 >= N_NODES) return;
    float4 acc0 = {0,0,0,0}, acc1 = {0,0,0,0}, acc2 = {0,0,0,0}, acc3 = {0,0,0,0};
    #pragma unroll 4
    for (int k = 0; k < H_DIM; k += 4) {
        float4 w0 = *(float4*)&Wl[(k + 0) * 64 + c4];
        float4 w1 = *(float4*)&Wl[(k + 1) * 64 + c4];
        float4 w2 = *(float4*)&Wl[(k + 2) * 64 + c4];
        float4 w3 = *(float4*)&Wl[(k + 3) * 64 + c4];
        float4 s4 = *(float4*)&scl[k];
        float4 f4 = *(float4*)&shl[k];
        #define DO_NODE(ACC, I)                                                        \
        {   h4 r = *(const h4*)&Z[(size_t)(n0 + I) * 64 + k];                          \
            float2 p = __half22float2(r.a), q = __half22float2(r.b);                   \
            float z0 = fmaf(p.x, s4.x, f4.x), z1 = fmaf(p.y, s4.y, f4.y);              \
            float z2 = fmaf(q.x, s4.z, f4.z), z3 = fmaf(q.y, s4.w, f4.w);              \
            fma4(ACC, z0, w0); fma4(ACC, z1, w1); fma4(ACC, z2, w2); fma4(ACC, z3, w3); }
        DO_NODE(acc0, 0) DO_NODE(acc1, 1) DO_NODE(acc2, 2) DO_NODE(acc3, 3)
        #undef DO_NODE
    }
    float d0 = dinv[n0], d1 = dinv[n0 + 1], d2 = dinv[n0 + 2], d3 = dinv[n0 + 3];
    acc0.x *= d0; acc0.y *= d0; acc0.z *= d0; acc0.w *= d0;
    acc1.x *= d1; acc1.y *= d1; acc1.z *= d1; acc1.w *= d1;
    acc2.x *= d2; acc2.y *= d2; acc2.z *= d2; acc2.w *= d2;
    acc3.x *= d3; acc3.y *= d3; acc3.z *= d3; acc3.w *= d3;
    *(h4*)&hp[(size_t)(n0 + 0) * 64 + c4] = pack_h4(acc0);
    *(h4*)&hp[(size_t)(n0 + 1) * 64 + c4] = pack_h4(acc1);
    *(h4*)&hp[(size_t)(n0 + 2) * 64 + c4] = pack_h4(acc2);
    *(h4*)&hp[(size_t)(n0 + 3) * 64 + c4] = pack_h4(acc3);
}

// ---------- aggregate + relu + fused BN partial stats ----------
// wave per node; 8 lane-groups of 8 handle 8 edges in flight; lane covers 8 channels (16B).
__global__ __launch_bounds__(256) void aggregate_k(
        const __half* __restrict__ hp, const float* __restrict__ dinv,
        const int* __restrict__ offsets, const int* __restrict__ counts,
        const unsigned short* __restrict__ ssrc, const float* __restrict__ bias,
        __half* __restrict__ zb, float* __restrict__ slots) {
    int wid = (blockIdx.x * blockDim.x + threadIdx.x) >> 6;   // node (grid exact)
    int lane = threadIdx.x & 63;
    int g = lane >> 3;            // edge sub-slot 0..7
    int c8 = (lane & 7) * 8;      // channel base
    float a0=0,a1=0,a2=0,a3=0,a4=0,a5=0,a6=0,a7=0;
    int s0 = offsets[wid];
    int ce = counts[wid];
    for (int e = g; e < ce; e += 8) {
        int s = ssrc[s0 + e];
        h8 v = *(const h8*)(hp + (size_t)s * 64 + c8);
        float2 f0 = __half22float2(v.a), f1 = __half22float2(v.b);
        float2 f2 = __half22float2(v.c), f3 = __half22float2(v.d);
        a0 += f0.x; a1 += f0.y; a2 += f1.x; a3 += f1.y;
        a4 += f2.x; a5 += f2.y; a6 += f3.x; a7 += f3.y;
    }
    #define RED(A) A += __shfl_xor(A, 8); A += __shfl_xor(A, 16); A += __shfl_xor(A, 32);
    RED(a0) RED(a1) RED(a2) RED(a3) RED(a4) RED(a5) RED(a6) RED(a7)
    #undef RED
    __shared__ float lds_s[4][64];
    __shared__ float lds_q[4][64];
    int w = threadIdx.x >> 6;
    if (g == 0) {
        h8 sv = *(const h8*)(hp + (size_t)wid * 64 + c8);
        float2 f0 = __half22float2(sv.a), f1 = __half22float2(sv.b);
        float2 f2 = __half22float2(sv.c), f3 = __half22float2(sv.d);
        float di = dinv[wid];
        float4 b0 = *(const float4*)&bias[c8];
        float4 b1 = *(const float4*)&bias[c8 + 4];
        float o0 = fmaxf(fmaf(a0 + f0.x, di, b0.x), 0.f);
        float o1 = fmaxf(fmaf(a1 + f0.y, di, b0.y), 0.f);
        float o2 = fmaxf(fmaf(a2 + f1.x, di, b0.z), 0.f);
        float o3 = fmaxf(fmaf(a3 + f1.y, di, b0.w), 0.f);
        float o4 = fmaxf(fmaf(a4 + f2.x, di, b1.x), 0.f);
        float o5 = fmaxf(fmaf(a5 + f2.y, di, b1.y), 0.f);
        float o6 = fmaxf(fmaf(a6 + f3.x, di, b1.z), 0.f);
        float o7 = fmaxf(fmaf(a7 + f3.y, di, b1.w), 0.f);
        h8 ov;
        ov.a = __float22half2_rn(make_float2(o0, o1));
        ov.b = __float22half2_rn(make_float2(o2, o3));
        ov.c = __float22half2_rn(make_float2(o4, o5));
        ov.d = __float22half2_rn(make_float2(o6, o7));
        *(h8*)(zb + (size_t)wid * 64 + c8) = ov;
        lds_s[w][c8+0]=o0; lds_s[w][c8+1]=o1; lds_s[w][c8+2]=o2; lds_s[w][c8+3]=o3;
        lds_s[w][c8+4]=o4; lds_s[w][c8+5]=o5; lds_s[w][c8+6]=o6; lds_s[w][c8+7]=o7;
        lds_q[w][c8+0]=o0*o0; lds_q[w][c8+1]=o1*o1; lds_q[w][c8+2]=o2*o2; lds_q[w][c8+3]=o3*o3;
        lds_q[w][c8+4]=o4*o4; lds_q[w][c8+5]=o5*o5; lds_q[w][c8+6]=o6*o6; lds_q[w][c8+7]=o7*o7;
    }
    __syncthreads();
    int c = threadIdx.x & 63;
    if (threadIdx.x < 64) {
        float t = lds_s[0][c] + lds_s[1][c] + lds_s[2][c] + lds_s[3][c];
        atomicAdd(&slots[(blockIdx.x & 63) * 128 + c], t);
    } else if (threadIdx.x < 128) {
        float t = lds_q[0][c] + lds_q[1][c] + lds_q[2][c] + lds_q[3][c];
        atomicAdd(&slots[(blockIdx.x & 63) * 128 + 64 + c], t);
    }
}

// reduce the 64 stat slots -> scale/shift, then re-zero slots for next layer
__global__ void bn_finalize_k(float* __restrict__ slots,
                              const float* __restrict__ gamma, const float* __restrict__ beta,
                              float* __restrict__ scale, float* __restrict__ shift) {
    __shared__ float red[128];
    int c = threadIdx.x;   // 0..127
    float s = 0.f;
    for (int b = 0; b < 64; b++) s += slots[b * 128 + c];
    red[c] = s;
    __syncthreads();
    if (c < 64) {
        float mu = red[c] * (1.0f / N_NODES);
        float var = red[c + 64] * (1.0f / N_NODES) - mu * mu;
        float k = gamma[c] * rsqrtf(var + EPS_BN);
        scale[c] = k;
        shift[c] = beta[c] - mu * k;
    }
    for (int i = c; i < 64 * 128; i += 128) slots[i] = 0.f;
}

// ---------- epilogue ----------

// one block (256 threads) per graph: vectorized mean-pool + fused affine + L2 norm.
// lane layout: slot = t&7 (channel octet), r = t>>3 (row phase 0..31).
__global__ __launch_bounds__(256) void pool_k(
        const __half* __restrict__ zb0, const __half* __restrict__ zb1,
        const __half* __restrict__ zb2,
        const float* __restrict__ scaleAll, const float* __restrict__ shiftAll,
        const int* __restrict__ batch, float* __restrict__ gc) {
    int g = blockIdx.x;
    int lo = 0, hi = N_NODES;
    while (lo < hi) { int mid = (lo + hi) >> 1; if (batch[mid] < g) lo = mid + 1; else hi = mid; }
    int start = lo;
    hi = N_NODES;
    while (lo < hi) { int mid = (lo + hi) >> 1; if (batch[mid] < g + 1) lo = mid + 1; else hi = mid; }
    int end = lo;

    int slot = threadIdx.x & 7;
    int r = threadIdx.x >> 3;        // 0..31
    const __half* zbs[3] = {zb0, zb1, zb2};
    float acc[3][8];
    #pragma unroll
    for (int l = 0; l < 3; l++)
        #pragma unroll
        for (int j = 0; j < 8; j++) acc[l][j] = 0.f;
    #pragma unroll
    for (int l = 0; l < 3; l++) {
        const __half* z = zbs[l];
        for (int n = start + r; n < end; n += 32) {
            h8 v = *(const h8*)(z + (size_t)n * 64 + slot * 8);
            float2 f0 = __half22float2(v.a), f1 = __half22float2(v.b);
            float2 f2 = __half22float2(v.c), f3 = __half22float2(v.d);
            acc[l][0] += f0.x; acc[l][1] += f0.y; acc[l][2] += f1.x; acc[l][3] += f1.y;
            acc[l][4] += f2.x; acc[l][5] += f2.y; acc[l][6] += f3.x; acc[l][7] += f3.y;
        }
    }
    // reduce the 8 in-wave row-phases (lanes differing in bits 3..5)
    #pragma unroll
    for (int l = 0; l < 3; l++)
        #pragma unroll
        for (int j = 0; j < 8; j++) {
            float a = acc[l][j];
            a += __shfl_xor(a, 8);
            a += __shfl_xor(a, 16);
            a += __shfl_xor(a, 32);
            acc[l][j] = a;
        }
    __shared__ float red[4][3][64];
    int w = threadIdx.x >> 6;
    if ((threadIdx.x & 63) < 8) {
        #pragma unroll
        for (int l = 0; l < 3; l++)
            #pragma unroll
            for (int j = 0; j < 8; j++)
                red[w][l][slot * 8 + j] = acc[l][j];
    }
    __syncthreads();
    __shared__ float part[4];
    int t = threadIdx.x;
    float m = 0.f;
    if (t < 192) {
        int l = t >> 6, ch = t & 63;
        float s = red[0][l][ch] + red[1][l][ch] + red[2][l][ch] + red[3][l][ch];
        m = (end > start) ? fmaf(scaleAll[t], s / (float)(end - start), shiftAll[t]) : 0.f;
    }
    float q = m * m;
    #pragma unroll
    for (int off = 32; off; off >>= 1) q += __shfl_xor(q, off);
    if ((t & 63) == 0) part[t >> 6] = q;
    __syncthreads();
    float inv = 1.0f / fmaxf(sqrtf(part[0] + part[1] + part[2] + part[3]), 1e-12f);
    if (t < 192) gc[(size_t)g * 192 + t] = m * inv;
}

// one wave per node: z = zb*scale+shift for 3 layers, L2 normalize, write zc fp32
__global__ __launch_bounds__(256) void l2norm_zc_k(
        const __half* __restrict__ zb0, const __half* __restrict__ zb1,
        const __half* __restrict__ zb2,
        const float* __restrict__ scaleAll, const float* __restrict__ shiftAll,
        float* __restrict__ zc) {
    int wid = (blockIdx.x * blockDim.x + threadIdx.x) >> 6;
    int lane = threadIdx.x & 63;
    float a = fmaf(__half2float(zb0[(size_t)wid * 64 + lane]), scaleAll[lane],       shiftAll[lane]);
    float b = fmaf(__half2float(zb1[(size_t)wid * 64 + lane]), scaleAll[64 + lane],  shiftAll[64 + lane]);
    float c = fmaf(__half2float(zb2[(size_t)wid * 64 + lane]), scaleAll[128 + lane], shiftAll[128 + lane]);
    float s = a * a + b * b + c * c;
    #pragma unroll
    for (int off = 32; off; off >>= 1) s += __shfl_xor(s, off);
    float inv = 1.0f / fmaxf(sqrtf(s), 1e-12f);
    float* row = zc + (size_t)wid * 192;
    row[lane] = a * inv; row[lane + 64] = b * inv; row[lane + 128] = c * inv;
}

// ---------- launch ----------

extern "C" void kernel_launch(void* const* d_in, const int* in_sizes, int n_in,
                              void* d_out, int out_size, void* d_ws, size_t ws_size,
                              hipStream_t stream) {
    const float* x     = (const float*)d_in[0];
    const int*   ei    = (const int*)d_in[1];
    const int*   batch = (const int*)d_in[2];
    const float* W[3]     = {(const float*)d_in[3],  (const float*)d_in[7],  (const float*)d_in[11]};
    const float* bias[3]  = {(const float*)d_in[4],  (const float*)d_in[8],  (const float*)d_in[12]};
    const float* gamma[3] = {(const float*)d_in[5],  (const float*)d_in[9],  (const float*)d_in[13]};
    const float* beta[3]  = {(const float*)d_in[6],  (const float*)d_in[10], (const float*)d_in[14]};
    const int* src = ei;
    const int* dst = ei + N_EDGES;

    float* out = (float*)d_out;
    float* zc = out;                                // [N, 192]
    float* gc = out + (size_t)N_NODES * 192;        // [G, 192]

    char* w = (char*)d_ws;
    auto alloc = [&](size_t bytes) -> void* {
        void* p = (void*)w;
        w += (bytes + 255) / 256 * 256;
        return p;
    };
    int*            counts    = (int*)alloc(N_NODES * 4);
    int*            offsets   = (int*)alloc(N_NODES * 4);
    int*            cursor    = (int*)alloc(N_NODES * 4);
    int*            blocksums = (int*)alloc(64 * 4);
    float*          dinv      = (float*)alloc(N_NODES * 4);
    unsigned short* ssrc      = (unsigned short*)alloc(N_EDGES * 2);
    __half*         hp        = (__half*)alloc((size_t)N_NODES * 64 * 2);
    __half*         zb[3];
    zb[0] = (__half*)alloc((size_t)N_NODES * 64 * 2);
    zb[1] = (__half*)alloc((size_t)N_NODES * 64 * 2);
    zb[2] = (__half*)alloc((size_t)N_NODES * 64 * 2);
    float*          slots     = (float*)alloc(64 * 128 * 4);
    float*          scaleAll  = (float*)alloc(192 * 4);
    float*          shiftAll  = (float*)alloc(192 * 4);

    const int nscan = (N_NODES + 1023) / 1024;   // 49

    hipMemsetAsync(counts, 0, N_NODES * 4, stream);
    hipMemsetAsync(slots, 0, 64 * 128 * 4, stream);
    count_edges_k<<<(N_EDGES / 4 + 255) / 256, 256, 0, stream>>>(dst, counts);
    scan_block_k<<<nscan, 1024, 0, stream>>>(counts, offsets, blocksums);
    scan_sums_k<<<1, 64, 0, stream>>>(blocksums, nscan);
    finalize_offsets_k<<<(N_NODES + 255) / 256, 256, 0, stream>>>(offsets, cursor, counts, blocksums, dinv);

    gemm0_fill_k<<<GEMM0_BLOCKS + FILL_BLOCKS, 256, 0, stream>>>(x, W[0], dinv, hp,
                                                                 src, dst, cursor, ssrc);

    const int aggBlocks = N_NODES / 4;   // 12500, exact

    for (int l = 0; l < 3; l++) {
        if (l > 0)
            gemm_h_k<<<GEMM0_BLOCKS, 256, 0, stream>>>(zb[l - 1], W[l],
                                                       scaleAll + (l - 1) * 64, shiftAll + (l - 1) * 64,
                                                       dinv, hp);
        aggregate_k<<<aggBlocks, 256, 0, stream>>>(hp, dinv, offsets, counts, ssrc,
                                                   bias[l], zb[l], slots);
        bn_finalize_k<<<1, 128, 0, stream>>>(slots, gamma[l], beta[l],
                                             scaleAll + l * 64, shiftAll + l * 64);
    }

    pool_k<<<N_GRAPHS, 256, 0, stream>>>(zb[0], zb[1], zb[2], scaleAll, shiftAll, batch, gc);
    l2norm_zc_k<<<N_NODES / 4, 256, 0, stream>>>(zb[0], zb[1], zb[2], scaleAll, shiftAll, zc);
}

// Round 5
// 274.616 us; speedup vs baseline: 2.7021x; 1.0175x over previous
//
#include <hip/hip_runtime.h>
#include <hip/hip_fp16.h>
#include <cstdint>
#include <cstddef>

#define N_NODES 50000
#define N_EDGES 800000
#define DIM_IN 128
#define H_DIM 64
#define N_GRAPHS 256
#define EPS_BN 1e-5f
#define GEMM0_BLOCKS 782       // ceil(50000/64)
#define FILL_CHUNKS 391        // ceil(800000/2048)
#define FILL_WINDOWS 4
#define FILL_BLOCKS (FILL_CHUNKS * FILL_WINDOWS)   // 1564
#define WINDOW_NODES 12500

struct __align__(16) h8 { __half2 a, b, c, d; };
struct __align__(8)  h4 { __half2 a, b; };

__device__ inline void fma4(float4& a, float s, const float4& w) {
    a.x = fmaf(s, w.x, a.x);
    a.y = fmaf(s, w.y, a.y);
    a.z = fmaf(s, w.z, a.z);
    a.w = fmaf(s, w.w, a.w);
}

__device__ inline h4 pack_h4(float4 v) {
    h4 r;
    r.a = __float22half2_rn(make_float2(v.x, v.y));
    r.b = __float22half2_rn(make_float2(v.z, v.w));
    return r;
}

// ---------- preprocessing ----------

__global__ void count_edges_k(const int* __restrict__ dst, int* __restrict__ counts) {
    int e4 = (blockIdx.x * blockDim.x + threadIdx.x) * 4;
    if (e4 >= N_EDGES) return;
    int4 d = *(const int4*)&dst[e4];
    atomicAdd(&counts[d.x], 1);
    atomicAdd(&counts[d.y], 1);
    atomicAdd(&counts[d.z], 1);
    atomicAdd(&counts[d.w], 1);
}

__global__ void scan_block_k(const int* __restrict__ counts, int* __restrict__ offsets,
                             int* __restrict__ blocksums) {
    __shared__ int sh[1024];
    int i = blockIdx.x * 1024 + threadIdx.x;
    int v = (i < N_NODES) ? counts[i] : 0;
    sh[threadIdx.x] = v;
    __syncthreads();
    for (int off = 1; off < 1024; off <<= 1) {
        int t = (threadIdx.x >= off) ? sh[threadIdx.x - off] : 0;
        __syncthreads();
        sh[threadIdx.x] += t;
        __syncthreads();
    }
    if (i < N_NODES) offsets[i] = sh[threadIdx.x] - v;   // exclusive
    if (threadIdx.x == 1023) blocksums[blockIdx.x] = sh[1023];
}

__global__ void scan_sums_k(int* blocksums, int nb) {
    if (threadIdx.x == 0 && blockIdx.x == 0) {
        int run = 0;
        for (int b = 0; b < nb; b++) { int t = blocksums[b]; blocksums[b] = run; run += t; }
    }
}

__global__ void finalize_offsets_k(int* __restrict__ offsets, int* __restrict__ cursor,
                                   const int* __restrict__ counts,
                                   const int* __restrict__ blocksums,
                                   float* __restrict__ dinv) {
    int i = blockIdx.x * blockDim.x + threadIdx.x;
    if (i >= N_NODES) return;
    int o = offsets[i] + blocksums[i >> 10];
    offsets[i] = o;
    cursor[i] = o;
    dinv[i] = rsqrtf((float)(counts[i] + 1));   // +1 self loop
}

// ---------- fused: windowed CSR fill + gemm layer 0 ----------
// fill blocks: window = bid&3 (XCD-affine under %8 round-robin), chunk = bid>>2.
// Each window's ssrc region (~400KB) stays L2-resident -> full-line assembly.

__global__ __launch_bounds__(256) void gemm0_fill_k(
        const float* __restrict__ X, const float* __restrict__ W,
        const float* __restrict__ dinv, __half* __restrict__ hp,
        const int* __restrict__ src, const int* __restrict__ dst,
        int* __restrict__ cursor, unsigned short* __restrict__ ssrc) {
    __shared__ float Wl[DIM_IN * 64];
    if (blockIdx.x < FILL_BLOCKS) {
        int win = blockIdx.x & (FILL_WINDOWS - 1);
        int c   = blockIdx.x >> 2;
        int lo = win * WINDOW_NODES;
        int hi = lo + WINDOW_NODES;
        #pragma unroll
        for (int rep = 0; rep < 2; rep++) {
            int idx = c * 2048 + rep * 1024 + threadIdx.x * 4;
            if (idx < N_EDGES) {
                int4 dv = *(const int4*)&dst[idx];
                int4 sv = *(const int4*)&src[idx];
                if (dv.x >= lo && dv.x < hi) ssrc[atomicAdd(&cursor[dv.x], 1)] = (unsigned short)sv.x;
                if (dv.y >= lo && dv.y < hi) ssrc[atomicAdd(&cursor[dv.y], 1)] = (unsigned short)sv.y;
                if (dv.z >= lo && dv.z < hi) ssrc[atomicAdd(&cursor[dv.z], 1)] = (unsigned short)sv.z;
                if (dv.w >= lo && dv.w < hi) ssrc[atomicAdd(&cursor[dv.w], 1)] = (unsigned short)sv.w;
            }
        }
        return;
    }
    int gb = blockIdx.x - FILL_BLOCKS;
    for (int i = threadIdx.x * 4; i < DIM_IN * 64; i += 256 * 4)
        *(float4*)&Wl[i] = *(const float4*)&W[i];
    __syncthreads();
    int c4 = (threadIdx.x & 15) * 4;
    int n0 = gb * 64 + (threadIdx.x >> 4) * 4;
    if (n0 >= N_NODES) return;
    const float* zr = X + (size_t)n0 * DIM_IN;
    float4 acc0 = {0,0,0,0}, acc1 = {0,0,0,0}, acc2 = {0,0,0,0}, acc3 = {0,0,0,0};
    #pragma unroll 4
    for (int k = 0; k < DIM_IN; k += 4) {
        float4 w0 = *(float4*)&Wl[(k + 0) * 64 + c4];
        float4 w1 = *(float4*)&Wl[(k + 1) * 64 + c4];
        float4 w2 = *(float4*)&Wl[(k + 2) * 64 + c4];
        float4 w3 = *(float4*)&Wl[(k + 3) * 64 + c4];
        float4 z0 = *(const float4*)&zr[0 * DIM_IN + k];
        float4 z1 = *(const float4*)&zr[1 * DIM_IN + k];
        float4 z2 = *(const float4*)&zr[2 * DIM_IN + k];
        float4 z3 = *(const float4*)&zr[3 * DIM_IN + k];
        fma4(acc0, z0.x, w0); fma4(acc0, z0.y, w1); fma4(acc0, z0.z, w2); fma4(acc0, z0.w, w3);
        fma4(acc1, z1.x, w0); fma4(acc1, z1.y, w1); fma4(acc1, z1.z, w2); fma4(acc1, z1.w, w3);
        fma4(acc2, z2.x, w0); fma4(acc2, z2.y, w1); fma4(acc2, z2.z, w2); fma4(acc2, z2.w, w3);
        fma4(acc3, z3.x, w0); fma4(acc3, z3.y, w1); fma4(acc3, z3.z, w2); fma4(acc3, z3.w, w3);
    }
    float d0 = dinv[n0], d1 = dinv[n0 + 1], d2 = dinv[n0 + 2], d3 = dinv[n0 + 3];
    acc0.x *= d0; acc0.y *= d0; acc0.z *= d0; acc0.w *= d0;
    acc1.x *= d1; acc1.y *= d1; acc1.z *= d1; acc1.w *= d1;
    acc2.x *= d2; acc2.y *= d2; acc2.z *= d2; acc2.w *= d2;
    acc3.x *= d3; acc3.y *= d3; acc3.z *= d3; acc3.w *= d3;
    *(h4*)&hp[(size_t)(n0 + 0) * 64 + c4] = pack_h4(acc0);
    *(h4*)&hp[(size_t)(n0 + 1) * 64 + c4] = pack_h4(acc1);
    *(h4*)&hp[(size_t)(n0 + 2) * 64 + c4] = pack_h4(acc2);
    *(h4*)&hp[(size_t)(n0 + 3) * 64 + c4] = pack_h4(acc3);
}

// ---------- gemm layers 1/2: fp16 zb input + BN affine, fp16*dinv out ----------

__global__ __launch_bounds__(256) void gemm_h_k(
        const __half* __restrict__ Z, const float* __restrict__ W,
        const float* __restrict__ scale, const float* __restrict__ shift,
        const float* __restrict__ dinv, __half* __restrict__ hp) {
    __shared__ float Wl[H_DIM * 64];
    __shared__ float scl[64], shl[64];
    for (int i = threadIdx.x * 4; i < H_DIM * 64; i += 256 * 4)
        *(float4*)&Wl[i] = *(const float4*)&W[i];
    if (threadIdx.x < 64) { scl[threadIdx.x] = scale[threadIdx.x]; shl[threadIdx.x] = shift[threadIdx.x]; }
    __syncthreads();
    int c4 = (threadIdx.x & 15) * 4;
    int n0 = blockIdx.x * 64 + (threadIdx.x >> 4) * 4;
    if (n0 >= N_NODES) return;
    float4 acc0 = {0,0,0,0}, acc1 = {0,0,0,0}, acc2 = {0,0,0,0}, acc3 = {0,0,0,0};
    #pragma unroll 4
    for (int k = 0; k < H_DIM; k += 4) {
        float4 w0 = *(float4*)&Wl[(k + 0) * 64 + c4];
        float4 w1 = *(float4*)&Wl[(k + 1) * 64 + c4];
        float4 w2 = *(float4*)&Wl[(k + 2) * 64 + c4];
        float4 w3 = *(float4*)&Wl[(k + 3) * 64 + c4];
        float4 s4 = *(float4*)&scl[k];
        float4 f4 = *(float4*)&shl[k];
        #define DO_NODE(ACC, I)                                                        \
        {   h4 r = *(const h4*)&Z[(size_t)(n0 + I) * 64 + k];                          \
            float2 p = __half22float2(r.a), q = __half22float2(r.b);                   \
            float z0 = fmaf(p.x, s4.x, f4.x), z1 = fmaf(p.y, s4.y, f4.y);              \
            float z2 = fmaf(q.x, s4.z, f4.z), z3 = fmaf(q.y, s4.w, f4.w);              \
            fma4(ACC, z0, w0); fma4(ACC, z1, w1); fma4(ACC, z2, w2); fma4(ACC, z3, w3); }
        DO_NODE(acc0, 0) DO_NODE(acc1, 1) DO_NODE(acc2, 2) DO_NODE(acc3, 3)
        #undef DO_NODE
    }
    float d0 = dinv[n0], d1 = dinv[n0 + 1], d2 = dinv[n0 + 2], d3 = dinv[n0 + 3];
    acc0.x *= d0; acc0.y *= d0; acc0.z *= d0; acc0.w *= d0;
    acc1.x *= d1; acc1.y *= d1; acc1.z *= d1; acc1.w *= d1;
    acc2.x *= d2; acc2.y *= d2; acc2.z *= d2; acc2.w *= d2;
    acc3.x *= d3; acc3.y *= d3; acc3.z *= d3; acc3.w *= d3;
    *(h4*)&hp[(size_t)(n0 + 0) * 64 + c4] = pack_h4(acc0);
    *(h4*)&hp[(size_t)(n0 + 1) * 64 + c4] = pack_h4(acc1);
    *(h4*)&hp[(size_t)(n0 + 2) * 64 + c4] = pack_h4(acc2);
    *(h4*)&hp[(size_t)(n0 + 3) * 64 + c4] = pack_h4(acc3);
}

// ---------- aggregate + relu + fused BN partial stats ----------

__global__ __launch_bounds__(256) void aggregate_k(
        const __half* __restrict__ hp, const float* __restrict__ dinv,
        const int* __restrict__ offsets, const int* __restrict__ counts,
        const unsigned short* __restrict__ ssrc, const float* __restrict__ bias,
        __half* __restrict__ zb, float* __restrict__ slots) {
    int wid = (blockIdx.x * blockDim.x + threadIdx.x) >> 6;   // node (grid exact)
    int lane = threadIdx.x & 63;
    int g = lane >> 3;            // edge sub-slot 0..7
    int c8 = (lane & 7) * 8;      // channel base
    float a0=0,a1=0,a2=0,a3=0,a4=0,a5=0,a6=0,a7=0;
    int s0 = offsets[wid];
    int ce = counts[wid];
    for (int e = g; e < ce; e += 8) {
        int s = ssrc[s0 + e];
        h8 v = *(const h8*)(hp + (size_t)s * 64 + c8);
        float2 f0 = __half22float2(v.a), f1 = __half22float2(v.b);
        float2 f2 = __half22float2(v.c), f3 = __half22float2(v.d);
        a0 += f0.x; a1 += f0.y; a2 += f1.x; a3 += f1.y;
        a4 += f2.x; a5 += f2.y; a6 += f3.x; a7 += f3.y;
    }
    #define RED(A) A += __shfl_xor(A, 8); A += __shfl_xor(A, 16); A += __shfl_xor(A, 32);
    RED(a0) RED(a1) RED(a2) RED(a3) RED(a4) RED(a5) RED(a6) RED(a7)
    #undef RED
    __shared__ float lds_s[4][64];
    __shared__ float lds_q[4][64];
    int w = threadIdx.x >> 6;
    if (g == 0) {
        h8 sv = *(const h8*)(hp + (size_t)wid * 64 + c8);
        float2 f0 = __half22float2(sv.a), f1 = __half22float2(sv.b);
        float2 f2 = __half22float2(sv.c), f3 = __half22float2(sv.d);
        float di = dinv[wid];
        float4 b0 = *(const float4*)&bias[c8];
        float4 b1 = *(const float4*)&bias[c8 + 4];
        float o0 = fmaxf(fmaf(a0 + f0.x, di, b0.x), 0.f);
        float o1 = fmaxf(fmaf(a1 + f0.y, di, b0.y), 0.f);
        float o2 = fmaxf(fmaf(a2 + f1.x, di, b0.z), 0.f);
        float o3 = fmaxf(fmaf(a3 + f1.y, di, b0.w), 0.f);
        float o4 = fmaxf(fmaf(a4 + f2.x, di, b1.x), 0.f);
        float o5 = fmaxf(fmaf(a5 + f2.y, di, b1.y), 0.f);
        float o6 = fmaxf(fmaf(a6 + f3.x, di, b1.z), 0.f);
        float o7 = fmaxf(fmaf(a7 + f3.y, di, b1.w), 0.f);
        h8 ov;
        ov.a = __float22half2_rn(make_float2(o0, o1));
        ov.b = __float22half2_rn(make_float2(o2, o3));
        ov.c = __float22half2_rn(make_float2(o4, o5));
        ov.d = __float22half2_rn(make_float2(o6, o7));
        *(h8*)(zb + (size_t)wid * 64 + c8) = ov;
        lds_s[w][c8+0]=o0; lds_s[w][c8+1]=o1; lds_s[w][c8+2]=o2; lds_s[w][c8+3]=o3;
        lds_s[w][c8+4]=o4; lds_s[w][c8+5]=o5; lds_s[w][c8+6]=o6; lds_s[w][c8+7]=o7;
        lds_q[w][c8+0]=o0*o0; lds_q[w][c8+1]=o1*o1; lds_q[w][c8+2]=o2*o2; lds_q[w][c8+3]=o3*o3;
        lds_q[w][c8+4]=o4*o4; lds_q[w][c8+5]=o5*o5; lds_q[w][c8+6]=o6*o6; lds_q[w][c8+7]=o7*o7;
    }
    __syncthreads();
    int c = threadIdx.x & 63;
    if (threadIdx.x < 64) {
        float t = lds_s[0][c] + lds_s[1][c] + lds_s[2][c] + lds_s[3][c];
        atomicAdd(&slots[(blockIdx.x & 63) * 128 + c], t);
    } else if (threadIdx.x < 128) {
        float t = lds_q[0][c] + lds_q[1][c] + lds_q[2][c] + lds_q[3][c];
        atomicAdd(&slots[(blockIdx.x & 63) * 128 + 64 + c], t);
    }
}

// reduce the 64 stat slots -> scale/shift, then re-zero slots for next layer
__global__ void bn_finalize_k(float* __restrict__ slots,
                              const float* __restrict__ gamma, const float* __restrict__ beta,
                              float* __restrict__ scale, float* __restrict__ shift) {
    __shared__ float red[128];
    int c = threadIdx.x;   // 0..127
    float s = 0.f;
    for (int b = 0; b < 64; b++) s += slots[b * 128 + c];
    red[c] = s;
    __syncthreads();
    if (c < 64) {
        float mu = red[c] * (1.0f / N_NODES);
        float var = red[c + 64] * (1.0f / N_NODES) - mu * mu;
        float k = gamma[c] * rsqrtf(var + EPS_BN);
        scale[c] = k;
        shift[c] = beta[c] - mu * k;
    }
    for (int i = c; i < 64 * 128; i += 128) slots[i] = 0.f;
}

// ---------- epilogue ----------

__global__ __launch_bounds__(256) void pool_k(
        const __half* __restrict__ zb0, const __half* __restrict__ zb1,
        const __half* __restrict__ zb2,
        const float* __restrict__ scaleAll, const float* __restrict__ shiftAll,
        const int* __restrict__ batch, float* __restrict__ gc) {
    int g = blockIdx.x;
    int lo = 0, hi = N_NODES;
    while (lo < hi) { int mid = (lo + hi) >> 1; if (batch[mid] < g) lo = mid + 1; else hi = mid; }
    int start = lo;
    hi = N_NODES;
    while (lo < hi) { int mid = (lo + hi) >> 1; if (batch[mid] < g + 1) lo = mid + 1; else hi = mid; }
    int end = lo;

    int slot = threadIdx.x & 7;
    int r = threadIdx.x >> 3;        // 0..31
    const __half* zbs[3] = {zb0, zb1, zb2};
    float acc[3][8];
    #pragma unroll
    for (int l = 0; l < 3; l++)
        #pragma unroll
        for (int j = 0; j < 8; j++) acc[l][j] = 0.f;
    #pragma unroll
    for (int l = 0; l < 3; l++) {
        const __half* z = zbs[l];
        for (int n = start + r; n < end; n += 32) {
            h8 v = *(const h8*)(z + (size_t)n * 64 + slot * 8);
            float2 f0 = __half22float2(v.a), f1 = __half22float2(v.b);
            float2 f2 = __half22float2(v.c), f3 = __half22float2(v.d);
            acc[l][0] += f0.x; acc[l][1] += f0.y; acc[l][2] += f1.x; acc[l][3] += f1.y;
            acc[l][4] += f2.x; acc[l][5] += f2.y; acc[l][6] += f3.x; acc[l][7] += f3.y;
        }
    }
    #pragma unroll
    for (int l = 0; l < 3; l++)
        #pragma unroll
        for (int j = 0; j < 8; j++) {
            float a = acc[l][j];
            a += __shfl_xor(a, 8);
            a += __shfl_xor(a, 16);
            a += __shfl_xor(a, 32);
            acc[l][j] = a;
        }
    __shared__ float red[4][3][64];
    int w = threadIdx.x >> 6;
    if ((threadIdx.x & 63) < 8) {
        #pragma unroll
        for (int l = 0; l < 3; l++)
            #pragma unroll
            for (int j = 0; j < 8; j++)
                red[w][l][slot * 8 + j] = acc[l][j];
    }
    __syncthreads();
    __shared__ float part[4];
    int t = threadIdx.x;
    float m = 0.f;
    if (t < 192) {
        int l = t >> 6, ch = t & 63;
        float s = red[0][l][ch] + red[1][l][ch] + red[2][l][ch] + red[3][l][ch];
        m = (end > start) ? fmaf(scaleAll[t], s / (float)(end - start), shiftAll[t]) : 0.f;
    }
    float q = m * m;
    #pragma unroll
    for (int off = 32; off; off >>= 1) q += __shfl_xor(q, off);
    if ((t & 63) == 0) part[t >> 6] = q;
    __syncthreads();
    float inv = 1.0f / fmaxf(sqrtf(part[0] + part[1] + part[2] + part[3]), 1e-12f);
    if (t < 192) gc[(size_t)g * 192 + t] = m * inv;
}

__global__ __launch_bounds__(256) void l2norm_zc_k(
        const __half* __restrict__ zb0, const __half* __restrict__ zb1,
        const __half* __restrict__ zb2,
        const float* __restrict__ scaleAll, const float* __restrict__ shiftAll,
        float* __restrict__ zc) {
    int wid = (blockIdx.x * blockDim.x + threadIdx.x) >> 6;
    int lane = threadIdx.x & 63;
    float a = fmaf(__half2float(zb0[(size_t)wid * 64 + lane]), scaleAll[lane],       shiftAll[lane]);
    float b = fmaf(__half2float(zb1[(size_t)wid * 64 + lane]), scaleAll[64 + lane],  shiftAll[64 + lane]);
    float c = fmaf(__half2float(zb2[(size_t)wid * 64 + lane]), scaleAll[128 + lane], shiftAll[128 + lane]);
    float s = a * a + b * b + c * c;
    #pragma unroll
    for (int off = 32; off; off >>= 1) s += __shfl_xor(s, off);
    float inv = 1.0f / fmaxf(sqrtf(s), 1e-12f);
    float* row = zc + (size_t)wid * 192;
    row[lane] = a * inv; row[lane + 64] = b * inv; row[lane + 128] = c * inv;
}

// ---------- launch ----------

extern "C" void kernel_launch(void* const* d_in, const int* in_sizes, int n_in,
                              void* d_out, int out_size, void* d_ws, size_t ws_size,
                              hipStream_t stream) {
    const float* x     = (const float*)d_in[0];
    const int*   ei    = (const int*)d_in[1];
    const int*   batch = (const int*)d_in[2];
    const float* W[3]     = {(const float*)d_in[3],  (const float*)d_in[7],  (const float*)d_in[11]};
    const float* bias[3]  = {(const float*)d_in[4],  (const float*)d_in[8],  (const float*)d_in[12]};
    const float* gamma[3] = {(const float*)d_in[5],  (const float*)d_in[9],  (const float*)d_in[13]};
    const float* beta[3]  = {(const float*)d_in[6],  (const float*)d_in[10], (const float*)d_in[14]};
    const int* src = ei;
    const int* dst = ei + N_EDGES;

    float* out = (float*)d_out;
    float* zc = out;                                // [N, 192]
    float* gc = out + (size_t)N_NODES * 192;        // [G, 192]

    char* w = (char*)d_ws;
    auto alloc = [&](size_t bytes) -> void* {
        void* p = (void*)w;
        w += (bytes + 255) / 256 * 256;
        return p;
    };
    int*            counts    = (int*)alloc(N_NODES * 4);
    int*            offsets   = (int*)alloc(N_NODES * 4);
    int*            cursor    = (int*)alloc(N_NODES * 4);
    int*            blocksums = (int*)alloc(64 * 4);
    float*          dinv      = (float*)alloc(N_NODES * 4);
    unsigned short* ssrc      = (unsigned short*)alloc(N_EDGES * 2);
    __half*         hp        = (__half*)alloc((size_t)N_NODES * 64 * 2);
    __half*         zb[3];
    zb[0] = (__half*)alloc((size_t)N_NODES * 64 * 2);
    zb[1] = (__half*)alloc((size_t)N_NODES * 64 * 2);
    zb[2] = (__half*)alloc((size_t)N_NODES * 64 * 2);
    float*          slots     = (float*)alloc(64 * 128 * 4);
    float*          scaleAll  = (float*)alloc(192 * 4);
    float*          shiftAll  = (float*)alloc(192 * 4);

    const int nscan = (N_NODES + 1023) / 1024;   // 49

    hipMemsetAsync(counts, 0, N_NODES * 4, stream);
    hipMemsetAsync(slots, 0, 64 * 128 * 4, stream);
    count_edges_k<<<(N_EDGES / 4 + 255) / 256, 256, 0, stream>>>(dst, counts);
    scan_block_k<<<nscan, 1024, 0, stream>>>(counts, offsets, blocksums);
    scan_sums_k<<<1, 64, 0, stream>>>(blocksums, nscan);
    finalize_offsets_k<<<(N_NODES + 255) / 256, 256, 0, stream>>>(offsets, cursor, counts, blocksums, dinv);

    gemm0_fill_k<<<FILL_BLOCKS + GEMM0_BLOCKS, 256, 0, stream>>>(x, W[0], dinv, hp,
                                                                 src, dst, cursor, ssrc);

    const int aggBlocks = N_NODES / 4;   // 12500, exact

    for (int l = 0; l < 3; l++) {
        if (l > 0)
            gemm_h_k<<<GEMM0_BLOCKS, 256, 0, stream>>>(zb[l - 1], W[l],
                                                       scaleAll + (l - 1) * 64, shiftAll + (l - 1) * 64,
                                                       dinv, hp);
        aggregate_k<<<aggBlocks, 256, 0, stream>>>(hp, dinv, offsets, counts, ssrc,
                                                   bias[l], zb[l], slots);
        bn_finalize_k<<<1, 128, 0, stream>>>(slots, gamma[l], beta[l],
                                             scaleAll + l * 64, shiftAll + l * 64);
    }

    pool_k<<<N_GRAPHS, 256, 0, stream>>>(zb[0], zb[1], zb[2], scaleAll, shiftAll, batch, gc);
    l2norm_zc_k<<<N_NODES / 4, 256, 0, stream>>>(zb[0], zb[1], zb[2], scaleAll, shiftAll, zc);
}